// Round 12
// baseline (4545.429 us; speedup 1.0000x reference)
//
#include <hip/hip_runtime.h>
#include <hip/hip_bf16.h>

static __device__ __forceinline__ float lrelu(float v){ return v >= 0.f ? v : 0.2f*v; }

// order-preserving float<->uint key for atomicMax on signed floats
static __device__ __forceinline__ unsigned fkey(float f){
    unsigned b = __float_as_uint(f);
    return (b & 0x80000000u) ? ~b : (b | 0x80000000u);
}
static __device__ __forceinline__ float funkey(unsigned k){
    unsigned b = (k & 0x80000000u) ? (k & 0x7FFFFFFFu) : ~k;
    return __uint_as_float(b);
}

// q slots: 0..2 sum(ea cols) | 3 sum(et2) | 4..6 g1 | 7 c1 | 8..11 g2 | 12 c2
//          16..19 vs1 | 20..23 vd1 | 24..27 as2[0],as2[1],ad2[0],ad2[1]

__global__ void __launch_bounds__(256)
k_sums(const float* __restrict__ ea, float* __restrict__ q, int E)
{
    float s0 = 0.f, s1 = 0.f, s2 = 0.f;
    int stride = gridDim.x * blockDim.x;
    for (int e = blockIdx.x*blockDim.x + threadIdx.x; e < E; e += stride){
        size_t o = 3*(size_t)e;
        s0 += ea[o]; s1 += ea[o+1]; s2 += ea[o+2];
    }
    for (int o = 32; o > 0; o >>= 1){
        s0 += __shfl_down(s0, o);
        s1 += __shfl_down(s1, o);
        s2 += __shfl_down(s2, o);
    }
    if ((threadIdx.x & 63) == 0){
        atomicAdd(&q[0], s0); atomicAdd(&q[1], s1); atomicAdd(&q[2], s2);
    }
}

// shown layouts: W1 (4,16), We1 (3,16), We2 (4,2), W2 (16,2), Wm (in,out)
__global__ void
k_prep(const float* __restrict__ W1, const float* __restrict__ as1,
       const float* __restrict__ ad1,
       const float* __restrict__ We1, const float* __restrict__ ae1,
       const float* __restrict__ We2, const float* __restrict__ ae2,
       const float* __restrict__ as2, const float* __restrict__ ad2,
       float* __restrict__ q, float invE)
{
    if (threadIdx.x != 0 || blockIdx.x != 0) return;
    float c1 = 0.f;
    for (int k = 0; k < 3; k++){
        float g = 0.f;
        for (int j = 0; j < 16; j++) g += We1[k*16 + j] * ae1[j];
        q[4+k] = g;
        c1 += q[k] * invE * g;
    }
    q[7] = c1;
    for (int k = 0; k < 4; k++)
        q[8+k] = We2[k*2] * ae2[0] + We2[k*2+1] * ae2[1];
    for (int c = 0; c < 4; c++){
        float vs = 0.f, vd = 0.f;
        for (int j = 0; j < 16; j++){
            float w = W1[c*16 + j];
            vs += w * as1[j];
            vd += w * ad1[j];
        }
        q[16+c] = vs; q[20+c] = vd;
    }
    q[24] = as2[0]; q[25] = as2[1]; q[26] = ad2[0]; q[27] = ad2[1];
}

static __device__ __forceinline__ float alpha1_of(int i, int E,
    const int* __restrict__ ei, const float* __restrict__ ea,
    const float* __restrict__ x, const float* __restrict__ q,
    int& s, int& d)
{
    float a;
    if (i < E){
        s = ei[i]; d = ei[E+i];
        const float* xs = x + 4*(size_t)s;
        const float* xd = x + 4*(size_t)d;
        size_t o = 3*(size_t)i;
        a = xs[0]*q[16] + xs[1]*q[17] + xs[2]*q[18] + xs[3]*q[19]
          + xd[0]*q[20] + xd[1]*q[21] + xd[2]*q[22] + xd[3]*q[23]
          + ea[o]*q[4] + ea[o+1]*q[5] + ea[o+2]*q[6];
    } else {
        s = d = i - E;
        const float* xs = x + 4*(size_t)s;
        a = xs[0]*(q[16]+q[20]) + xs[1]*(q[17]+q[21])
          + xs[2]*(q[18]+q[22]) + xs[3]*(q[19]+q[23]) + q[7];
    }
    return lrelu(a);
}

__global__ void __launch_bounds__(256)
k_m1(const int* __restrict__ ei, const float* __restrict__ ea,
     const float* __restrict__ x, const float* __restrict__ q,
     unsigned int* __restrict__ m1, int E, int N)
{
    int i = blockIdx.x*256 + threadIdx.x;
    if (i >= E + N) return;
    int s, d;
    float a = alpha1_of(i, E, ei, ea, x, q, s, d);
    atomicMax(&m1[d], fkey(a));
}

__global__ void __launch_bounds__(256)
k_z1(const int* __restrict__ ei, const float* __restrict__ ea,
     const float* __restrict__ x, const float* __restrict__ q,
     const unsigned int* __restrict__ m1, float* __restrict__ z1, int E, int N)
{
    int i = blockIdx.x*256 + threadIdx.x;
    if (i >= E + N) return;
    int s, d;
    float a = alpha1_of(i, E, ei, ea, x, q, s, d);
    float p = expf(a - funkey(m1[d]));
    atomicAdd(&z1[d], p);
}

__global__ void __launch_bounds__(256)
k_aggr1(const int* __restrict__ ei, const float* __restrict__ ea,
        const float* __restrict__ x, const float* __restrict__ W1,
        const float* __restrict__ q, const unsigned int* __restrict__ m1,
        const float* __restrict__ z1, float* __restrict__ x1, int E, int N)
{
    __shared__ float W[64];
    if (threadIdx.x < 64) W[threadIdx.x] = W1[threadIdx.x];
    __syncthreads();
    int i = blockIdx.x*256 + threadIdx.x;
    if (i >= E + N) return;
    int s, d;
    float a = alpha1_of(i, E, ei, ea, x, q, s, d);
    float p = expf(a - funkey(m1[d]));
    float w = p / z1[d];
    const float* xs = x + 4*(size_t)s;
    float x0 = xs[0], x1v = xs[1], x2 = xs[2], x3 = xs[3];
    float* dst = x1 + 16*(size_t)d;
    for (int j = 0; j < 16; j++){
        float h = x0*W[j] + x1v*W[16+j] + x2*W[32+j] + x3*W[48+j];
        atomicAdd(dst + j, w*h);
    }
}

__global__ void __launch_bounds__(256)
k_fin1(float* __restrict__ x1, const float* __restrict__ b1,
       const float* __restrict__ W2, float* __restrict__ h2, int N)
{
    __shared__ float sb[16], sW[32];
    int t = threadIdx.x;
    if (t < 16) sb[t] = b1[t];
    else if (t < 48) sW[t-16] = W2[t-16];
    __syncthreads();
    int n = blockIdx.x*256 + t;
    if (n >= N) return;
    float* row = x1 + 16*(size_t)n;
    float p0 = 0.f, p1 = 0.f;
    for (int j = 0; j < 16; j++){
        float v = row[j] + sb[j];
        row[j] = v;
        p0 += v * sW[2*j];
        p1 += v * sW[2*j+1];
    }
    h2[2*(size_t)n]   = p0;
    h2[2*(size_t)n+1] = p1;
}

__global__ void __launch_bounds__(256)
k_mlp(const int* __restrict__ ei, const float* __restrict__ ea,
      const float* __restrict__ x1,
      const float* __restrict__ Wm1, const float* __restrict__ bm1,
      const float* __restrict__ Wm2, const float* __restrict__ bm2,
      const float* __restrict__ Wm3, const float* __restrict__ bm3,
      const float* __restrict__ Wm4, const float* __restrict__ bm4,
      const float* __restrict__ q, float* __restrict__ qw,
      float* __restrict__ et2, float* __restrict__ oute, int E)
{
    __shared__ float L[1020];
    for (int t = threadIdx.x; t < 1020; t += 256){
        float v;
        if      (t < 560)  v = Wm1[t];
        else if (t < 576)  v = bm1[t-560];
        else if (t < 832)  v = Wm2[t-576];
        else if (t < 848)  v = bm2[t-832];
        else if (t < 976)  v = Wm3[t-848];
        else if (t < 984)  v = bm3[t-976];
        else if (t < 1016) v = Wm4[t-984];
        else               v = bm4[t-1016];
        L[t] = v;
    }
    __syncthreads();
    const float* w1 = L;       const float* c1 = L+560;
    const float* w2 = L+576;   const float* c2 = L+832;
    const float* w3 = L+848;   const float* c3 = L+976;
    const float* w4 = L+984;   const float* c4 = L+1016;

    int e = blockIdx.x*256 + threadIdx.x;
    float et = 0.f;
    if (e < E){
        int si = ei[e], di = ei[E+e];
        const float* rs = x1 + 16*(size_t)si;
        const float* rd = x1 + 16*(size_t)di;
        size_t eo = 3*(size_t)e;
        float zc[35];
        for (int j = 0; j < 16; j++) zc[j] = rs[j];
        zc[16] = ea[eo]; zc[17] = ea[eo+1]; zc[18] = ea[eo+2];
        for (int j = 0; j < 16; j++) zc[19+j] = rd[j];

        float u1[16];
        for (int j = 0; j < 16; j++){
            float a = c1[j];
            for (int c = 0; c < 35; c++) a += zc[c]*w1[c*16+j];
            u1[j] = fmaxf(a, 0.f);
        }
        float u2[16];
        for (int j = 0; j < 16; j++){
            float a = c2[j];
            for (int c = 0; c < 16; c++) a += u1[c]*w2[c*16+j];
            u2[j] = fmaxf(a, 0.f);
        }
        float u3[8];
        for (int j = 0; j < 8; j++){
            float a = c3[j];
            for (int c = 0; c < 16; c++) a += u2[c]*w3[c*8+j];
            u3[j] = fmaxf(a, 0.f);
        }
        float ev[4];
        for (int j = 0; j < 4; j++){
            float a = c4[j];
            for (int c = 0; c < 8; c++) a += u3[c]*w4[c*4+j];
            ev[j] = a;
        }
        float mx = fmaxf(fmaxf(ev[0],ev[1]), fmaxf(ev[2],ev[3]));
        float ls = logf(expf(ev[0]-mx)+expf(ev[1]-mx)+expf(ev[2]-mx)+expf(ev[3]-mx)) + mx;
        float4 o;
        o.x = ev[0]-ls; o.y = ev[1]-ls; o.z = ev[2]-ls; o.w = ev[3]-ls;
        ((float4*)oute)[e] = o;
        et = ev[0]*q[8] + ev[1]*q[9] + ev[2]*q[10] + ev[3]*q[11];
        et2[e] = et;
    }
    float t0 = et;
    for (int o = 32; o > 0; o >>= 1) t0 += __shfl_down(t0, o);
    if ((threadIdx.x & 63) == 0) atomicAdd(&qw[3], t0);
}

__global__ void
k_c2(float* __restrict__ q, float invE)
{
    if (threadIdx.x == 0 && blockIdx.x == 0) q[12] = q[3] * invE;
}

static __device__ __forceinline__ float alpha2_of(int i, int E,
    const int* __restrict__ ei, const float* __restrict__ et2,
    const float* __restrict__ h2, const float* __restrict__ q,
    int& s, int& d)
{
    float et;
    if (i < E){
        s = ei[i]; d = ei[E+i];
        et = et2[i];
    } else {
        s = d = i - E;
        et = q[12];
    }
    float hs2 = h2[2*(size_t)s]*q[24] + h2[2*(size_t)s+1]*q[25];
    float hd2 = h2[2*(size_t)d]*q[26] + h2[2*(size_t)d+1]*q[27];
    return lrelu(hs2 + hd2 + et);
}

__global__ void __launch_bounds__(256)
k_m2(const int* __restrict__ ei, const float* __restrict__ et2,
     const float* __restrict__ h2, const float* __restrict__ q,
     unsigned int* __restrict__ m2, int E, int N)
{
    int i = blockIdx.x*256 + threadIdx.x;
    if (i >= E + N) return;
    int s, d;
    float a = alpha2_of(i, E, ei, et2, h2, q, s, d);
    atomicMax(&m2[d], fkey(a));
}

__global__ void __launch_bounds__(256)
k_z2(const int* __restrict__ ei, const float* __restrict__ et2,
     const float* __restrict__ h2, const float* __restrict__ q,
     const unsigned int* __restrict__ m2, float* __restrict__ z2, int E, int N)
{
    int i = blockIdx.x*256 + threadIdx.x;
    if (i >= E + N) return;
    int s, d;
    float a = alpha2_of(i, E, ei, et2, h2, q, s, d);
    float p = expf(a - funkey(m2[d]));
    atomicAdd(&z2[d], p);
}

__global__ void __launch_bounds__(256)
k_aggr2(const int* __restrict__ ei, const float* __restrict__ et2,
        const float* __restrict__ h2, const float* __restrict__ q,
        const unsigned int* __restrict__ m2, const float* __restrict__ z2,
        float* __restrict__ x2a, int E, int N)
{
    int i = blockIdx.x*256 + threadIdx.x;
    if (i >= E + N) return;
    int s, d;
    float a = alpha2_of(i, E, ei, et2, h2, q, s, d);
    float p = expf(a - funkey(m2[d]));
    float w = p / z2[d];
    atomicAdd(&x2a[2*(size_t)d],   w*h2[2*(size_t)s]);
    atomicAdd(&x2a[2*(size_t)d+1], w*h2[2*(size_t)s+1]);
}

__global__ void __launch_bounds__(256)
k_out(const float* __restrict__ x2a, const float* __restrict__ b2,
      float* __restrict__ outn, int N)
{
    int n = blockIdx.x*256 + threadIdx.x;
    if (n >= N) return;
    float v0 = x2a[2*(size_t)n]   + b2[0];
    float v1 = x2a[2*(size_t)n+1] + b2[1];
    float m = fmaxf(v0, v1);
    float ls = logf(expf(v0-m) + expf(v1-m)) + m;
    float2 o;
    o.x = v0 - ls;
    o.y = v1 - ls;
    ((float2*)outn)[n] = o;
}

extern "C" void kernel_launch(void* const* d_in, const int* in_sizes, int n_in,
                              void* d_out, int out_size, void* d_ws, size_t ws_size,
                              hipStream_t stream)
{
    const float* x   = (const float*)d_in[0];
    const int*   ei  = (const int*)  d_in[1];
    const float* ea  = (const float*)d_in[2];
    const float* W1  = (const float*)d_in[3];
    const float* as1 = (const float*)d_in[4];
    const float* ad1 = (const float*)d_in[5];
    const float* We1 = (const float*)d_in[6];
    const float* ae1 = (const float*)d_in[7];
    const float* b1  = (const float*)d_in[8];
    const float* Wm1 = (const float*)d_in[9];
    const float* bm1 = (const float*)d_in[10];
    const float* Wm2 = (const float*)d_in[11];
    const float* bm2 = (const float*)d_in[12];
    const float* Wm3 = (const float*)d_in[13];
    const float* bm3 = (const float*)d_in[14];
    const float* Wm4 = (const float*)d_in[15];
    const float* bm4 = (const float*)d_in[16];
    const float* W2  = (const float*)d_in[17];
    const float* as2 = (const float*)d_in[18];
    const float* ad2 = (const float*)d_in[19];
    const float* We2 = (const float*)d_in[20];
    const float* ae2 = (const float*)d_in[21];
    const float* b2  = (const float*)d_in[22];

    const int N = in_sizes[0] / 4;
    const int E = in_sizes[1] / 2;
    const int M = E + N;

    // ws: q(64) | mA(N) | zA(N) | x1(16N) | x2a(2N) | h2(2N) | et2(E)
    // total = 64 + 22N + E floats = 30.6 MB (round-7-proven budget)
    size_t needFloats = 64 + 22*(size_t)N + (size_t)E;
    if (ws_size < needFloats*sizeof(float)) return;

    float* ws  = (float*)d_ws;
    float* q   = ws;
    float* mA  = ws + 64;                 // m1 then m2 (uint keys)
    float* zA  = mA + N;                  // z1 then z2
    float* x1  = zA + N;
    float* x2a = x1 + 16*(size_t)N;
    float* h2  = x2a + 2*(size_t)N;
    float* et2 = h2 + 2*(size_t)N;

    // zero q, mA, zA, x1, x2a (= 64 + 20N floats)
    hipMemsetAsync(d_ws, 0, (64 + 20*(size_t)N)*sizeof(float), stream);

    float* outn = (float*)d_out;
    float* oute = outn + 2*(size_t)N;

    int nb_n = (N + 255) / 256;
    int nb_m = (M + 255) / 256;
    int nb_e = (E + 255) / 256;
    float invE = 1.0f / (float)E;

    k_sums<<<1024,256,0,stream>>>(ea, q, E);
    k_prep<<<1,64,0,stream>>>(W1, as1, ad1, We1, ae1, We2, ae2, as2, ad2, q, invE);
    k_m1<<<nb_m,256,0,stream>>>(ei, ea, x, q, (unsigned int*)mA, E, N);
    k_z1<<<nb_m,256,0,stream>>>(ei, ea, x, q, (const unsigned int*)mA, zA, E, N);
    k_aggr1<<<nb_m,256,0,stream>>>(ei, ea, x, W1, q, (const unsigned int*)mA, zA, x1, E, N);
    k_fin1<<<nb_n,256,0,stream>>>(x1, b1, W2, h2, N);
    k_mlp<<<nb_e,256,0,stream>>>(ei, ea, x1, Wm1, bm1, Wm2, bm2, Wm3, bm3,
                                 Wm4, bm4, q, q, et2, oute, E);
    k_c2<<<1,64,0,stream>>>(q, invE);
    // re-zero mA/zA for layer 2
    hipMemsetAsync((void*)mA, 0, 2*(size_t)N*sizeof(float), stream);
    k_m2<<<nb_m,256,0,stream>>>(ei, et2, h2, q, (unsigned int*)mA, E, N);
    k_z2<<<nb_m,256,0,stream>>>(ei, et2, h2, q, (const unsigned int*)mA, zA, E, N);
    k_aggr2<<<nb_m,256,0,stream>>>(ei, et2, h2, q, (const unsigned int*)mA, zA, x2a, E, N);
    k_out<<<nb_n,256,0,stream>>>(x2a, b2, outn, N);
}

// Round 13
// 2880.108 us; speedup vs baseline: 1.5782x; 1.5782x over previous
//
#include <hip/hip_runtime.h>
#include <hip/hip_bf16.h>

static __device__ __forceinline__ float lrelu(float v){ return v >= 0.f ? v : 0.2f*v; }

// order-preserving float<->uint key for atomicMax on signed floats
static __device__ __forceinline__ unsigned fkey(float f){
    unsigned b = __float_as_uint(f);
    return (b & 0x80000000u) ? ~b : (b | 0x80000000u);
}
static __device__ __forceinline__ float funkey(unsigned k){
    unsigned b = (k & 0x80000000u) ? (k & 0x7FFFFFFFu) : ~k;
    return __uint_as_float(b);
}

// q slots (256 floats):
// 0..2 sum(ea cols) | 3 sum(et2) | 4..6 g1 | 7 c1 | 8..11 g2 | 12 c2
// 16..19 vs1 | 20..23 vd1 | 24..27 as2[0],as2[1],ad2[0],ad2[1]
// 28..35 PM[c*2+r] = W1@W2 | 36..37 Q = b1@W2
// 64..127 A = W1@Wm1[0:16] | 128..191 B = W1@Wm1[19:35] | 192..207 bb

__global__ void __launch_bounds__(256)
k_sums(const float* __restrict__ ea, float* __restrict__ q, int E)
{
    float s0 = 0.f, s1 = 0.f, s2 = 0.f;
    int stride = gridDim.x * blockDim.x;
    for (int e = blockIdx.x*blockDim.x + threadIdx.x; e < E; e += stride){
        size_t o = 3*(size_t)e;
        s0 += ea[o]; s1 += ea[o+1]; s2 += ea[o+2];
    }
    for (int o = 32; o > 0; o >>= 1){
        s0 += __shfl_down(s0, o);
        s1 += __shfl_down(s1, o);
        s2 += __shfl_down(s2, o);
    }
    if ((threadIdx.x & 63) == 0){
        atomicAdd(&q[0], s0); atomicAdd(&q[1], s1); atomicAdd(&q[2], s2);
    }
}

// shown layouts: W1 (4,16), We1 (3,16), We2 (4,2), W2 (16,2), Wm (in,out)
__global__ void
k_prep(const float* __restrict__ W1, const float* __restrict__ as1,
       const float* __restrict__ ad1,
       const float* __restrict__ We1, const float* __restrict__ ae1,
       const float* __restrict__ b1,
       const float* __restrict__ Wm1, const float* __restrict__ bm1,
       const float* __restrict__ W2, const float* __restrict__ as2,
       const float* __restrict__ ad2,
       const float* __restrict__ We2, const float* __restrict__ ae2,
       float* __restrict__ q, float invE)
{
    int t = threadIdx.x;
    if (t < 16){
        int j = t;
        float a0=0,a1=0,a2=0,a3=0, c0=0,c1v=0,c2v=0,c3=0, tb=0;
        for (int i = 0; i < 16; i++){
            float wt = Wm1[i*16 + j];
            float wb = Wm1[(19+i)*16 + j];
            a0 += W1[0*16+i]*wt; a1 += W1[1*16+i]*wt;
            a2 += W1[2*16+i]*wt; a3 += W1[3*16+i]*wt;
            c0 += W1[0*16+i]*wb; c1v += W1[1*16+i]*wb;
            c2v += W1[2*16+i]*wb; c3 += W1[3*16+i]*wb;
            tb += b1[i]*(wt + wb);
        }
        q[64 + 0*16 + j] = a0; q[64 + 1*16 + j] = a1;
        q[64 + 2*16 + j] = a2; q[64 + 3*16 + j] = a3;
        q[128 + 0*16 + j] = c0; q[128 + 1*16 + j] = c1v;
        q[128 + 2*16 + j] = c2v; q[128 + 3*16 + j] = c3;
        q[192 + j] = bm1[j] + tb;
    } else if (t < 20){
        int c = t - 16;
        float vs = 0.f, vd = 0.f, p0 = 0.f, p1 = 0.f;
        for (int i = 0; i < 16; i++){
            float w = W1[c*16 + i];
            vs += w * as1[i];
            vd += w * ad1[i];
            p0 += w * W2[i*2 + 0];
            p1 += w * W2[i*2 + 1];
        }
        q[16+c] = vs; q[20+c] = vd;
        q[28 + c*2 + 0] = p0; q[28 + c*2 + 1] = p1;
    } else if (t == 20){
        float c1 = 0.f;
        for (int k = 0; k < 3; k++){
            float g = 0.f;
            for (int j = 0; j < 16; j++) g += We1[k*16 + j] * ae1[j];
            q[4+k] = g;
            c1 += q[k] * invE * g;
        }
        q[7] = c1;
    } else if (t == 21){
        for (int k = 0; k < 4; k++)
            q[8+k] = We2[k*2] * ae2[0] + We2[k*2+1] * ae2[1];
        q[24] = as2[0]; q[25] = as2[1]; q[26] = ad2[0]; q[27] = ad2[1];
    } else if (t == 22){
        float q0 = 0.f, q1 = 0.f;
        for (int i = 0; i < 16; i++){
            q0 += b1[i] * W2[i*2];
            q1 += b1[i] * W2[i*2+1];
        }
        q[36] = q0; q[37] = q1;
    }
}

static __device__ __forceinline__ float alpha1_of(int i, int E,
    const int* __restrict__ ei, const float* __restrict__ ea,
    const float* __restrict__ x, const float* __restrict__ q,
    int& s, int& d)
{
    float a;
    if (i < E){
        s = ei[i]; d = ei[E+i];
        const float* xs = x + 4*(size_t)s;
        const float* xd = x + 4*(size_t)d;
        size_t o = 3*(size_t)i;
        a = xs[0]*q[16] + xs[1]*q[17] + xs[2]*q[18] + xs[3]*q[19]
          + xd[0]*q[20] + xd[1]*q[21] + xd[2]*q[22] + xd[3]*q[23]
          + ea[o]*q[4] + ea[o+1]*q[5] + ea[o+2]*q[6];
    } else {
        s = d = i - E;
        const float* xs = x + 4*(size_t)s;
        a = xs[0]*(q[16]+q[20]) + xs[1]*(q[17]+q[21])
          + xs[2]*(q[18]+q[22]) + xs[3]*(q[19]+q[23]) + q[7];
    }
    return lrelu(a);
}

__global__ void __launch_bounds__(256)
k_m1(const int* __restrict__ ei, const float* __restrict__ ea,
     const float* __restrict__ x, const float* __restrict__ q,
     unsigned int* __restrict__ m1, int E, int N)
{
    int i = blockIdx.x*256 + threadIdx.x;
    if (i >= E + N) return;
    int s, d;
    float a = alpha1_of(i, E, ei, ea, x, q, s, d);
    atomicMax(&m1[d], fkey(a));
}

__global__ void __launch_bounds__(256)
k_z1(const int* __restrict__ ei, const float* __restrict__ ea,
     const float* __restrict__ x, const float* __restrict__ q,
     const unsigned int* __restrict__ m1, float* __restrict__ z1, int E, int N)
{
    int i = blockIdx.x*256 + threadIdx.x;
    if (i >= E + N) return;
    int s, d;
    float a = alpha1_of(i, E, ei, ea, x, q, s, d);
    float p = expf(a - funkey(m1[d]));
    atomicAdd(&z1[d], p);
}

// aggregate 4-dim x (not 16-dim h): xagg[d] += w * x[s]
__global__ void __launch_bounds__(256)
k_aggr1(const int* __restrict__ ei, const float* __restrict__ ea,
        const float* __restrict__ x, const float* __restrict__ q,
        const unsigned int* __restrict__ m1, const float* __restrict__ z1,
        float* __restrict__ xagg, int E, int N)
{
    int i = blockIdx.x*256 + threadIdx.x;
    if (i >= E + N) return;
    int s, d;
    float a = alpha1_of(i, E, ei, ea, x, q, s, d);
    float p = expf(a - funkey(m1[d]));
    float w = p / z1[d];
    const float* xs = x + 4*(size_t)s;
    float* dst = xagg + 4*(size_t)d;
    atomicAdd(dst + 0, w*xs[0]);
    atomicAdd(dst + 1, w*xs[1]);
    atomicAdd(dst + 2, w*xs[2]);
    atomicAdd(dst + 3, w*xs[3]);
}

// h2[n] = xagg[n] . PM + Q   (x1 never materialized)
__global__ void __launch_bounds__(256)
k_h2(const float* __restrict__ xagg, const float* __restrict__ q,
     float* __restrict__ h2, int N)
{
    int n = blockIdx.x*256 + threadIdx.x;
    if (n >= N) return;
    const float* xa = xagg + 4*(size_t)n;
    float p0 = xa[0]*q[28] + xa[1]*q[30] + xa[2]*q[32] + xa[3]*q[34] + q[36];
    float p1 = xa[0]*q[29] + xa[1]*q[31] + xa[2]*q[33] + xa[3]*q[35] + q[37];
    h2[2*(size_t)n]   = p0;
    h2[2*(size_t)n+1] = p1;
}

__global__ void __launch_bounds__(256)
k_mlp(const int* __restrict__ ei, const float* __restrict__ ea,
      const float* __restrict__ xagg,
      const float* __restrict__ Wm1, const float* __restrict__ Wm2,
      const float* __restrict__ bm2, const float* __restrict__ Wm3,
      const float* __restrict__ bm3, const float* __restrict__ Wm4,
      const float* __restrict__ bm4,
      const float* __restrict__ q, float* __restrict__ qw,
      float* __restrict__ et2, float* __restrict__ oute, int E)
{
    __shared__ float L[640];
    for (int t = threadIdx.x; t < 640; t += 256){
        float v;
        if      (t < 128)  v = q[64 + t];           // A[64] then B[64]
        else if (t < 144)  v = q[192 + (t-128)];    // bb[16]
        else if (t < 192)  v = Wm1[256 + (t-144)];  // Wm1 rows 16..18 (ea part)
        else if (t < 448)  v = Wm2[t-192];
        else if (t < 464)  v = bm2[t-448];
        else if (t < 592)  v = Wm3[t-464];
        else if (t < 600)  v = bm3[t-592];
        else if (t < 632)  v = Wm4[t-600];
        else if (t < 636)  v = bm4[t-632];
        else               v = q[8 + (t-636)];      // g2[4]
        L[t] = v;
    }
    __syncthreads();
    const float* A   = L;
    const float* B   = L + 64;
    const float* bb  = L + 128;
    const float* C3  = L + 144;
    const float* w2  = L + 192;  const float* c2 = L + 448;
    const float* w3  = L + 464;  const float* c3 = L + 592;
    const float* w4  = L + 600;  const float* c4 = L + 632;
    const float* g2  = L + 636;

    int e = blockIdx.x*256 + threadIdx.x;
    float et = 0.f;
    if (e < E){
        int si = ei[e], di = ei[E+e];
        const float* xs = xagg + 4*(size_t)si;
        const float* xd = xagg + 4*(size_t)di;
        float s0 = xs[0], s1 = xs[1], s2 = xs[2], s3 = xs[3];
        float d0 = xd[0], d1 = xd[1], d2 = xd[2], d3 = xd[3];
        size_t eo = 3*(size_t)e;
        float e0 = ea[eo], e1 = ea[eo+1], e2v = ea[eo+2];

        float u1[16];
        for (int j = 0; j < 16; j++){
            float a = bb[j]
                + s0*A[j] + s1*A[16+j] + s2*A[32+j] + s3*A[48+j]
                + e0*C3[j] + e1*C3[16+j] + e2v*C3[32+j]
                + d0*B[j] + d1*B[16+j] + d2*B[32+j] + d3*B[48+j];
            u1[j] = fmaxf(a, 0.f);
        }
        float u2[16];
        for (int j = 0; j < 16; j++){
            float a = c2[j];
            for (int c = 0; c < 16; c++) a += u1[c]*w2[c*16+j];
            u2[j] = fmaxf(a, 0.f);
        }
        float u3[8];
        for (int j = 0; j < 8; j++){
            float a = c3[j];
            for (int c = 0; c < 16; c++) a += u2[c]*w3[c*8+j];
            u3[j] = fmaxf(a, 0.f);
        }
        float ev[4];
        for (int j = 0; j < 4; j++){
            float a = c4[j];
            for (int c = 0; c < 8; c++) a += u3[c]*w4[c*4+j];
            ev[j] = a;
        }
        float mx = fmaxf(fmaxf(ev[0],ev[1]), fmaxf(ev[2],ev[3]));
        float ls = logf(expf(ev[0]-mx)+expf(ev[1]-mx)+expf(ev[2]-mx)+expf(ev[3]-mx)) + mx;
        float4 o;
        o.x = ev[0]-ls; o.y = ev[1]-ls; o.z = ev[2]-ls; o.w = ev[3]-ls;
        ((float4*)oute)[e] = o;
        et = ev[0]*g2[0] + ev[1]*g2[1] + ev[2]*g2[2] + ev[3]*g2[3];
        et2[e] = et;
    }
    float t0 = et;
    for (int o = 32; o > 0; o >>= 1) t0 += __shfl_down(t0, o);
    if ((threadIdx.x & 63) == 0) atomicAdd(&qw[3], t0);
}

__global__ void
k_c2(float* __restrict__ q, float invE)
{
    if (threadIdx.x == 0 && blockIdx.x == 0) q[12] = q[3] * invE;
}

static __device__ __forceinline__ float alpha2_of(int i, int E,
    const int* __restrict__ ei, const float* __restrict__ et2,
    const float* __restrict__ h2, const float* __restrict__ q,
    int& s, int& d)
{
    float et;
    if (i < E){
        s = ei[i]; d = ei[E+i];
        et = et2[i];
    } else {
        s = d = i - E;
        et = q[12];
    }
    float hs2 = h2[2*(size_t)s]*q[24] + h2[2*(size_t)s+1]*q[25];
    float hd2 = h2[2*(size_t)d]*q[26] + h2[2*(size_t)d+1]*q[27];
    return lrelu(hs2 + hd2 + et);
}

__global__ void __launch_bounds__(256)
k_m2(const int* __restrict__ ei, const float* __restrict__ et2,
     const float* __restrict__ h2, const float* __restrict__ q,
     unsigned int* __restrict__ m2, int E, int N)
{
    int i = blockIdx.x*256 + threadIdx.x;
    if (i >= E + N) return;
    int s, d;
    float a = alpha2_of(i, E, ei, et2, h2, q, s, d);
    atomicMax(&m2[d], fkey(a));
}

__global__ void __launch_bounds__(256)
k_z2(const int* __restrict__ ei, const float* __restrict__ et2,
     const float* __restrict__ h2, const float* __restrict__ q,
     const unsigned int* __restrict__ m2, float* __restrict__ z2, int E, int N)
{
    int i = blockIdx.x*256 + threadIdx.x;
    if (i >= E + N) return;
    int s, d;
    float a = alpha2_of(i, E, ei, et2, h2, q, s, d);
    float p = expf(a - funkey(m2[d]));
    atomicAdd(&z2[d], p);
}

__global__ void __launch_bounds__(256)
k_aggr2(const int* __restrict__ ei, const float* __restrict__ et2,
        const float* __restrict__ h2, const float* __restrict__ q,
        const unsigned int* __restrict__ m2, const float* __restrict__ z2,
        float* __restrict__ x2a, int E, int N)
{
    int i = blockIdx.x*256 + threadIdx.x;
    if (i >= E + N) return;
    int s, d;
    float a = alpha2_of(i, E, ei, et2, h2, q, s, d);
    float p = expf(a - funkey(m2[d]));
    float w = p / z2[d];
    atomicAdd(&x2a[2*(size_t)d],   w*h2[2*(size_t)s]);
    atomicAdd(&x2a[2*(size_t)d+1], w*h2[2*(size_t)s+1]);
}

__global__ void __launch_bounds__(256)
k_out(const float* __restrict__ x2a, const float* __restrict__ b2,
      float* __restrict__ outn, int N)
{
    int n = blockIdx.x*256 + threadIdx.x;
    if (n >= N) return;
    float v0 = x2a[2*(size_t)n]   + b2[0];
    float v1 = x2a[2*(size_t)n+1] + b2[1];
    float m = fmaxf(v0, v1);
    float ls = logf(expf(v0-m) + expf(v1-m)) + m;
    float2 o;
    o.x = v0 - ls;
    o.y = v1 - ls;
    ((float2*)outn)[n] = o;
}

extern "C" void kernel_launch(void* const* d_in, const int* in_sizes, int n_in,
                              void* d_out, int out_size, void* d_ws, size_t ws_size,
                              hipStream_t stream)
{
    const float* x   = (const float*)d_in[0];
    const int*   ei  = (const int*)  d_in[1];
    const float* ea  = (const float*)d_in[2];
    const float* W1  = (const float*)d_in[3];
    const float* as1 = (const float*)d_in[4];
    const float* ad1 = (const float*)d_in[5];
    const float* We1 = (const float*)d_in[6];
    const float* ae1 = (const float*)d_in[7];
    const float* b1  = (const float*)d_in[8];
    const float* Wm1 = (const float*)d_in[9];
    const float* bm1 = (const float*)d_in[10];
    const float* Wm2 = (const float*)d_in[11];
    const float* bm2 = (const float*)d_in[12];
    const float* Wm3 = (const float*)d_in[13];
    const float* bm3 = (const float*)d_in[14];
    const float* Wm4 = (const float*)d_in[15];
    const float* bm4 = (const float*)d_in[16];
    const float* W2  = (const float*)d_in[17];
    const float* as2 = (const float*)d_in[18];
    const float* ad2 = (const float*)d_in[19];
    const float* We2 = (const float*)d_in[20];
    const float* ae2 = (const float*)d_in[21];
    const float* b2  = (const float*)d_in[22];

    const int N = in_sizes[0] / 4;
    const int E = in_sizes[1] / 2;
    const int M = E + N;

    // ws: q(256) | mA(N) | zA(N) | xagg(4N) | x2a(2N) | h2(2N) | et2(E)
    // total = 256 + 10N + E floats ~= 21.6 MB (under round-7-proven 30.6 MB)
    size_t needFloats = 256 + 10*(size_t)N + (size_t)E;
    if (ws_size < needFloats*sizeof(float)) return;

    float* ws   = (float*)d_ws;
    float* q    = ws;
    float* mA   = ws + 256;               // m1 then m2 (uint keys)
    float* zA   = mA + N;                 // z1 then z2
    float* xagg = zA + N;
    float* x2a  = xagg + 4*(size_t)N;
    float* h2   = x2a + 2*(size_t)N;
    float* et2  = h2 + 2*(size_t)N;

    // zero q, mA, zA, xagg, x2a (= 256 + 8N floats)
    hipMemsetAsync(d_ws, 0, (256 + 8*(size_t)N)*sizeof(float), stream);

    float* outn = (float*)d_out;
    float* oute = outn + 2*(size_t)N;

    int nb_n = (N + 255) / 256;
    int nb_m = (M + 255) / 256;
    int nb_e = (E + 255) / 256;
    float invE = 1.0f / (float)E;

    k_sums<<<1024,256,0,stream>>>(ea, q, E);
    k_prep<<<1,64,0,stream>>>(W1, as1, ad1, We1, ae1, b1, Wm1, bm1,
                              W2, as2, ad2, We2, ae2, q, invE);
    k_m1<<<nb_m,256,0,stream>>>(ei, ea, x, q, (unsigned int*)mA, E, N);
    k_z1<<<nb_m,256,0,stream>>>(ei, ea, x, q, (const unsigned int*)mA, zA, E, N);
    k_aggr1<<<nb_m,256,0,stream>>>(ei, ea, x, q, (const unsigned int*)mA, zA, xagg, E, N);
    k_h2<<<nb_n,256,0,stream>>>(xagg, q, h2, N);
    k_mlp<<<nb_e,256,0,stream>>>(ei, ea, xagg, Wm1, Wm2, bm2, Wm3, bm3,
                                 Wm4, bm4, q, q, et2, oute, E);
    k_c2<<<1,64,0,stream>>>(q, invE);
    hipMemsetAsync((void*)mA, 0, 2*(size_t)N*sizeof(float), stream);
    k_m2<<<nb_m,256,0,stream>>>(ei, et2, h2, q, (unsigned int*)mA, E, N);
    k_z2<<<nb_m,256,0,stream>>>(ei, et2, h2, q, (const unsigned int*)mA, zA, E, N);
    k_aggr2<<<nb_m,256,0,stream>>>(ei, et2, h2, q, (const unsigned int*)mA, zA, x2a, E, N);
    k_out<<<nb_n,256,0,stream>>>(x2a, b2, outn, N);
}

// Round 15
// 2020.540 us; speedup vs baseline: 2.2496x; 1.4254x over previous
//
#include <hip/hip_runtime.h>
#include <hip/hip_bf16.h>

static __device__ __forceinline__ float lrelu(float v){ return v >= 0.f ? v : 0.2f*v; }

static __device__ __forceinline__ unsigned fkey(float f){
    unsigned b = __float_as_uint(f);
    return (b & 0x80000000u) ? ~b : (b | 0x80000000u);
}
static __device__ __forceinline__ float funkey(unsigned k){
    unsigned b = (k & 0x80000000u) ? (k & 0x7FFFFFFFu) : ~k;
    return __uint_as_float(b);
}

// NOTE: parameter names must not collide with member names .x/.y/.z/.w
#define FMA4(D_, S_, V_) { D_.x += (S_)*(V_).x; D_.y += (S_)*(V_).y; \
                           D_.z += (S_)*(V_).z; D_.w += (S_)*(V_).w; }

// q slots (256 floats):
// 0..2 sum(ea cols) | 3 sum(et2) | 4..6 g1 | 7 c1 | 8..11 g2 | 12 c2
// 16..19 vs1 | 20..23 vd1 | 28..35 PM | 36..37 Q
// 40..43 S | 44 s0 | 45..48 D | 49 d0
// 64..127 A=W1@Wm1_top | 128..191 B=W1@Wm1_bot | 192..207 bb

__global__ void __launch_bounds__(256)
k_sums(const float* __restrict__ ea, float* __restrict__ q, int E)
{
    float s0 = 0.f, s1 = 0.f, s2 = 0.f;
    int stride = gridDim.x * blockDim.x;
    for (int e = blockIdx.x*blockDim.x + threadIdx.x; e < E; e += stride){
        size_t o = 3*(size_t)e;
        s0 += ea[o]; s1 += ea[o+1]; s2 += ea[o+2];
    }
    for (int o = 32; o > 0; o >>= 1){
        s0 += __shfl_down(s0, o);
        s1 += __shfl_down(s1, o);
        s2 += __shfl_down(s2, o);
    }
    if ((threadIdx.x & 63) == 0){
        atomicAdd(&q[0], s0); atomicAdd(&q[1], s1); atomicAdd(&q[2], s2);
    }
}

__global__ void
k_prep(const float* __restrict__ W1, const float* __restrict__ as1,
       const float* __restrict__ ad1,
       const float* __restrict__ We1, const float* __restrict__ ae1,
       const float* __restrict__ b1,
       const float* __restrict__ Wm1, const float* __restrict__ bm1,
       const float* __restrict__ W2, const float* __restrict__ as2,
       const float* __restrict__ ad2,
       const float* __restrict__ We2, const float* __restrict__ ae2,
       float* __restrict__ q, float invE)
{
    __shared__ float sPM[8], sQ[2];
    int t = threadIdx.x;
    if (t < 16){
        int j = t;
        float a0=0,a1=0,a2=0,a3=0, c0=0,c1v=0,c2v=0,c3=0, tb=0;
        for (int i = 0; i < 16; i++){
            float wt = Wm1[i*16 + j];
            float wb = Wm1[(19+i)*16 + j];
            a0 += W1[0*16+i]*wt; a1 += W1[1*16+i]*wt;
            a2 += W1[2*16+i]*wt; a3 += W1[3*16+i]*wt;
            c0 += W1[0*16+i]*wb; c1v += W1[1*16+i]*wb;
            c2v += W1[2*16+i]*wb; c3 += W1[3*16+i]*wb;
            tb += b1[i]*(wt + wb);
        }
        q[64+0*16+j] = a0; q[64+1*16+j] = a1; q[64+2*16+j] = a2; q[64+3*16+j] = a3;
        q[128+0*16+j] = c0; q[128+1*16+j] = c1v; q[128+2*16+j] = c2v; q[128+3*16+j] = c3;
        q[192+j] = bm1[j] + tb;
    } else if (t < 20){
        int c = t - 16;
        float vs = 0.f, vd = 0.f, p0 = 0.f, p1 = 0.f;
        for (int i = 0; i < 16; i++){
            float w = W1[c*16 + i];
            vs += w * as1[i];
            vd += w * ad1[i];
            p0 += w * W2[i*2 + 0];
            p1 += w * W2[i*2 + 1];
        }
        q[16+c] = vs; q[20+c] = vd;
        q[28+c*2+0] = p0; q[28+c*2+1] = p1;
        sPM[c*2+0] = p0; sPM[c*2+1] = p1;
    } else if (t == 20){
        float c1 = 0.f;
        for (int k = 0; k < 3; k++){
            float g = 0.f;
            for (int j = 0; j < 16; j++) g += We1[k*16 + j] * ae1[j];
            q[4+k] = g;
            c1 += q[k] * invE * g;
        }
        q[7] = c1;
    } else if (t == 21){
        for (int k = 0; k < 4; k++)
            q[8+k] = We2[k*2] * ae2[0] + We2[k*2+1] * ae2[1];
    } else if (t == 22){
        float q0 = 0.f, q1 = 0.f;
        for (int i = 0; i < 16; i++){
            q0 += b1[i] * W2[i*2];
            q1 += b1[i] * W2[i*2+1];
        }
        q[36] = q0; q[37] = q1;
        sQ[0] = q0; sQ[1] = q1;
    }
    __syncthreads();
    if (t == 0){
        float a0 = as2[0], a1 = as2[1], d0 = ad2[0], d1 = ad2[1];
        for (int c = 0; c < 4; c++){
            q[40+c] = sPM[c*2]*a0 + sPM[c*2+1]*a1;
            q[45+c] = sPM[c*2]*d0 + sPM[c*2+1]*d1;
        }
        q[44] = sQ[0]*a0 + sQ[1]*a1;
        q[49] = sQ[0]*d0 + sQ[1]*d1;
    }
}

// layer-1 alpha + p; store p; accumulate z1
__global__ void __launch_bounds__(256)
k_z1(const int* __restrict__ ei, const float* __restrict__ ea,
     const float* __restrict__ x, const float* __restrict__ q,
     float* __restrict__ pbuf, float* __restrict__ z1, int E, int N)
{
    int i = blockIdx.x*256 + threadIdx.x;
    if (i >= E + N) return;
    int s, d;
    float a;
    if (i < E){
        s = ei[i]; d = ei[E+i];
        const float* xs = x + 4*(size_t)s;
        const float* xd = x + 4*(size_t)d;
        size_t o = 3*(size_t)i;
        a = xs[0]*q[16] + xs[1]*q[17] + xs[2]*q[18] + xs[3]*q[19]
          + xd[0]*q[20] + xd[1]*q[21] + xd[2]*q[22] + xd[3]*q[23]
          + ea[o]*q[4] + ea[o+1]*q[5] + ea[o+2]*q[6];
    } else {
        s = d = i - E;
        const float* xs = x + 4*(size_t)s;
        a = xs[0]*(q[16]+q[20]) + xs[1]*(q[17]+q[21])
          + xs[2]*(q[18]+q[22]) + xs[3]*(q[19]+q[23]) + q[7];
    }
    float p = expf(fminf(lrelu(a), 60.0f));
    pbuf[i] = p;
    atomicAdd(&z1[d], p);
}

__global__ void __launch_bounds__(256)
k_aggr1(const int* __restrict__ ei, const float* __restrict__ x,
        const float* __restrict__ pbuf, const float* __restrict__ z1,
        float* __restrict__ xagg, int E, int N)
{
    int i = blockIdx.x*256 + threadIdx.x;
    if (i >= E + N) return;
    int s, d;
    if (i < E){ s = ei[i]; d = ei[E+i]; }
    else { s = d = i - E; }
    float w = pbuf[i] / z1[d];
    const float* xs = x + 4*(size_t)s;
    float* dst = xagg + 4*(size_t)d;
    atomicAdd(dst + 0, w*xs[0]);
    atomicAdd(dst + 1, w*xs[1]);
    atomicAdd(dst + 2, w*xs[2]);
    atomicAdd(dst + 3, w*xs[3]);
}

// h2[n] (for aggr2) and hsd2[n] = hs2+hd2 (self-loop alpha2 term)
__global__ void __launch_bounds__(256)
k_h2(const float* __restrict__ xagg, const float* __restrict__ q,
     float* __restrict__ h2, float* __restrict__ hsd2, int N)
{
    int n = blockIdx.x*256 + threadIdx.x;
    if (n >= N) return;
    const float* xa = xagg + 4*(size_t)n;
    float p0 = xa[0]*q[28] + xa[1]*q[30] + xa[2]*q[32] + xa[3]*q[34] + q[36];
    float p1 = xa[0]*q[29] + xa[1]*q[31] + xa[2]*q[33] + xa[3]*q[35] + q[37];
    h2[2*(size_t)n]   = p0;
    h2[2*(size_t)n+1] = p1;
    float hs = xa[0]*q[40] + xa[1]*q[41] + xa[2]*q[42] + xa[3]*q[43] + q[44];
    float hd = xa[0]*q[45] + xa[1]*q[46] + xa[2]*q[47] + xa[3]*q[48] + q[49];
    hsd2[n] = hs + hd;
}

__global__ void __launch_bounds__(256)
k_mlp(const int* __restrict__ ei, const float* __restrict__ ea,
      const float* __restrict__ xagg,
      const float* __restrict__ Wm1, const float* __restrict__ Wm2,
      const float* __restrict__ bm2, const float* __restrict__ Wm3,
      const float* __restrict__ bm3, const float* __restrict__ Wm4,
      const float* __restrict__ bm4,
      const float* __restrict__ q, float* __restrict__ qw,
      float* __restrict__ a2buf, unsigned int* __restrict__ m2,
      float* __restrict__ oute, int E)
{
    __shared__ __align__(16) float L[656];
    __shared__ float R[256];
    for (int t = threadIdx.x; t < 656; t += 256){
        float v;
        if      (t < 128)  v = q[64 + t];           // A then B
        else if (t < 144)  v = q[192 + (t-128)];    // bb
        else if (t < 192)  v = Wm1[256 + (t-144)];  // C3 = Wm1 rows 16..18
        else if (t < 448)  v = Wm2[t-192];
        else if (t < 464)  v = bm2[t-448];
        else if (t < 592)  v = Wm3[t-464];
        else if (t < 600)  v = bm3[t-592];
        else if (t < 632)  v = Wm4[t-600];
        else if (t < 636)  v = bm4[t-632];
        else if (t < 640)  v = q[8 + (t-636)];      // g2
        else               v = q[40 + (t-640)];     // S,s0,D,d0
        L[t] = v;
    }
    __syncthreads();
    const float4* A4  = (const float4*)(L);        // [r*4 + j4]
    const float4* B4  = (const float4*)(L + 64);
    const float4* bb4 = (const float4*)(L + 128);
    const float4* C34 = (const float4*)(L + 144);
    const float4* W24 = (const float4*)(L + 192);  // [c*4 + j4]
    const float4* B24 = (const float4*)(L + 448);
    const float4* W34 = (const float4*)(L + 464);  // [c*2 + j4]
    const float4* B34 = (const float4*)(L + 592);
    const float4* W44 = (const float4*)(L + 600);  // [c]
    const float*  sg2 = L + 636;
    const float*  SD  = L + 640;

    int e = blockIdx.x*256 + threadIdx.x;
    float et = 0.f;
    if (e < E){
        int si = ei[e], di = ei[E+e];
        float4 xs = ((const float4*)xagg)[si];
        float4 xd = ((const float4*)xagg)[di];
        size_t eo = 3*(size_t)e;
        float e0 = ea[eo], e1 = ea[eo+1], e2v = ea[eo+2];

        float u1[16];
        #pragma unroll
        for (int j4 = 0; j4 < 4; j4++){
            float4 acc = bb4[j4];
            FMA4(acc, xs.x, A4[0*4+j4]); FMA4(acc, xs.y, A4[1*4+j4]);
            FMA4(acc, xs.z, A4[2*4+j4]); FMA4(acc, xs.w, A4[3*4+j4]);
            FMA4(acc, e0, C34[0*4+j4]); FMA4(acc, e1, C34[1*4+j4]);
            FMA4(acc, e2v, C34[2*4+j4]);
            FMA4(acc, xd.x, B4[0*4+j4]); FMA4(acc, xd.y, B4[1*4+j4]);
            FMA4(acc, xd.z, B4[2*4+j4]); FMA4(acc, xd.w, B4[3*4+j4]);
            u1[j4*4+0] = fmaxf(acc.x, 0.f);
            u1[j4*4+1] = fmaxf(acc.y, 0.f);
            u1[j4*4+2] = fmaxf(acc.z, 0.f);
            u1[j4*4+3] = fmaxf(acc.w, 0.f);
        }

        float4 v0 = B24[0], v1 = B24[1], v2 = B24[2], v3 = B24[3];
        #pragma unroll
        for (int c = 0; c < 16; c++){
            float uc = u1[c];
            FMA4(v0, uc, W24[c*4+0]);
            FMA4(v1, uc, W24[c*4+1]);
            FMA4(v2, uc, W24[c*4+2]);
            FMA4(v3, uc, W24[c*4+3]);
        }
        float u2[16];
        u2[0]=fmaxf(v0.x,0.f); u2[1]=fmaxf(v0.y,0.f); u2[2]=fmaxf(v0.z,0.f); u2[3]=fmaxf(v0.w,0.f);
        u2[4]=fmaxf(v1.x,0.f); u2[5]=fmaxf(v1.y,0.f); u2[6]=fmaxf(v1.z,0.f); u2[7]=fmaxf(v1.w,0.f);
        u2[8]=fmaxf(v2.x,0.f); u2[9]=fmaxf(v2.y,0.f); u2[10]=fmaxf(v2.z,0.f); u2[11]=fmaxf(v2.w,0.f);
        u2[12]=fmaxf(v3.x,0.f); u2[13]=fmaxf(v3.y,0.f); u2[14]=fmaxf(v3.z,0.f); u2[15]=fmaxf(v3.w,0.f);

        float4 w0 = B34[0], w1 = B34[1];
        #pragma unroll
        for (int c = 0; c < 16; c++){
            float uc = u2[c];
            FMA4(w0, uc, W34[c*2+0]);
            FMA4(w1, uc, W34[c*2+1]);
        }
        float u3[8];
        u3[0]=fmaxf(w0.x,0.f); u3[1]=fmaxf(w0.y,0.f); u3[2]=fmaxf(w0.z,0.f); u3[3]=fmaxf(w0.w,0.f);
        u3[4]=fmaxf(w1.x,0.f); u3[5]=fmaxf(w1.y,0.f); u3[6]=fmaxf(w1.z,0.f); u3[7]=fmaxf(w1.w,0.f);

        float4 ev = *(const float4*)(L + 632);  // bm4
        #pragma unroll
        for (int c = 0; c < 8; c++){
            float uc = u3[c];
            FMA4(ev, uc, W44[c]);
        }

        float mx = fmaxf(fmaxf(ev.x, ev.y), fmaxf(ev.z, ev.w));
        float ls = logf(expf(ev.x-mx)+expf(ev.y-mx)+expf(ev.z-mx)+expf(ev.w-mx)) + mx;
        float4 o;
        o.x = ev.x-ls; o.y = ev.y-ls; o.z = ev.z-ls; o.w = ev.w-ls;
        ((float4*)oute)[e] = o;

        et = ev.x*sg2[0] + ev.y*sg2[1] + ev.z*sg2[2] + ev.w*sg2[3];
        float hs2 = xs.x*SD[0] + xs.y*SD[1] + xs.z*SD[2] + xs.w*SD[3] + SD[4];
        float hd2 = xd.x*SD[5] + xd.y*SD[6] + xd.z*SD[7] + xd.w*SD[8] + SD[9];
        float a2 = lrelu(hs2 + hd2 + et);
        a2buf[e] = a2;
        atomicMax(&m2[di], fkey(a2));
    }
    // block-level sum of et -> 1 atomic per block
    R[threadIdx.x] = et;
    __syncthreads();
    for (int off = 128; off > 0; off >>= 1){
        if (threadIdx.x < off) R[threadIdx.x] += R[threadIdx.x + off];
        __syncthreads();
    }
    if (threadIdx.x == 0) atomicAdd(&qw[3], R[0]);
}

__global__ void
k_c2(float* __restrict__ q, float invE)
{
    if (threadIdx.x == 0 && blockIdx.x == 0) q[12] = q[3] * invE;
}

__global__ void __launch_bounds__(256)
k_selfm2(const float* __restrict__ hsd2, const float* __restrict__ q,
         unsigned int* __restrict__ m2, int N)
{
    int n = blockIdx.x*256 + threadIdx.x;
    if (n >= N) return;
    float a = lrelu(hsd2[n] + q[12]);
    atomicMax(&m2[n], fkey(a));
}

__global__ void __launch_bounds__(256)
k_z2(const int* __restrict__ ei, const float* __restrict__ a2buf,
     const float* __restrict__ hsd2, const float* __restrict__ q,
     const unsigned int* __restrict__ m2, float* __restrict__ z2, int E, int N)
{
    int i = blockIdx.x*256 + threadIdx.x;
    if (i >= E + N) return;
    int d; float a;
    if (i < E){ d = ei[E+i]; a = a2buf[i]; }
    else { d = i - E; a = lrelu(hsd2[d] + q[12]); }
    float p = expf(a - funkey(m2[d]));
    atomicAdd(&z2[d], p);
}

__global__ void __launch_bounds__(256)
k_aggr2(const int* __restrict__ ei, const float* __restrict__ a2buf,
        const float* __restrict__ hsd2, const float* __restrict__ h2,
        const float* __restrict__ q, const unsigned int* __restrict__ m2,
        const float* __restrict__ z2, float* __restrict__ x2a, int E, int N)
{
    int i = blockIdx.x*256 + threadIdx.x;
    if (i >= E + N) return;
    int s, d; float a;
    if (i < E){ s = ei[i]; d = ei[E+i]; a = a2buf[i]; }
    else { s = d = i - E; a = lrelu(hsd2[d] + q[12]); }
    float p = expf(a - funkey(m2[d]));
    float w = p / z2[d];
    atomicAdd(&x2a[2*(size_t)d],   w*h2[2*(size_t)s]);
    atomicAdd(&x2a[2*(size_t)d+1], w*h2[2*(size_t)s+1]);
}

__global__ void __launch_bounds__(256)
k_out(const float* __restrict__ x2a, const float* __restrict__ b2,
      float* __restrict__ outn, int N)
{
    int n = blockIdx.x*256 + threadIdx.x;
    if (n >= N) return;
    float v0 = x2a[2*(size_t)n]   + b2[0];
    float v1 = x2a[2*(size_t)n+1] + b2[1];
    float m = fmaxf(v0, v1);
    float ls = logf(expf(v0-m) + expf(v1-m)) + m;
    float2 o;
    o.x = v0 - ls;
    o.y = v1 - ls;
    ((float2*)outn)[n] = o;
}

extern "C" void kernel_launch(void* const* d_in, const int* in_sizes, int n_in,
                              void* d_out, int out_size, void* d_ws, size_t ws_size,
                              hipStream_t stream)
{
    const float* x   = (const float*)d_in[0];
    const int*   ei  = (const int*)  d_in[1];
    const float* ea  = (const float*)d_in[2];
    const float* W1  = (const float*)d_in[3];
    const float* as1 = (const float*)d_in[4];
    const float* ad1 = (const float*)d_in[5];
    const float* We1 = (const float*)d_in[6];
    const float* ae1 = (const float*)d_in[7];
    const float* b1  = (const float*)d_in[8];
    const float* Wm1 = (const float*)d_in[9];
    const float* bm1 = (const float*)d_in[10];
    const float* Wm2 = (const float*)d_in[11];
    const float* bm2 = (const float*)d_in[12];
    const float* Wm3 = (const float*)d_in[13];
    const float* bm3 = (const float*)d_in[14];
    const float* Wm4 = (const float*)d_in[15];
    const float* bm4 = (const float*)d_in[16];
    const float* W2  = (const float*)d_in[17];
    const float* as2 = (const float*)d_in[18];
    const float* ad2 = (const float*)d_in[19];
    const float* We2 = (const float*)d_in[20];
    const float* ae2 = (const float*)d_in[21];
    const float* b2  = (const float*)d_in[22];

    const int N = in_sizes[0] / 4;
    const int E = in_sizes[1] / 2;
    const int M = E + N;

    // ws: q(256) | m2(N) | z1(N) | z2(N) | xagg(4N) | x2a(2N) | h2(2N) | hsd2(N) | pbuf(M)
    // total = 256 + 13N + E floats ~= 23.4 MB (< proven 30.6 MB)
    size_t needFloats = 256 + 13*(size_t)N + (size_t)E;
    if (ws_size < needFloats*sizeof(float)) return;

    float* ws   = (float*)d_ws;
    float* q    = ws;
    float* m2   = ws + 256;               // uint keys
    float* z1   = m2 + N;
    float* z2   = z1 + N;
    float* xagg = z2 + N;
    float* x2a  = xagg + 4*(size_t)N;
    float* h2   = x2a + 2*(size_t)N;
    float* hsd2 = h2 + 2*(size_t)N;
    float* pbuf = hsd2 + N;               // p1 (layer1) then a2 (layer2, first E slots)

    // zero q, m2, z1, z2, xagg, x2a
    hipMemsetAsync(d_ws, 0, (256 + 9*(size_t)N)*sizeof(float), stream);

    float* outn = (float*)d_out;
    float* oute = outn + 2*(size_t)N;

    int nb_n = (N + 255) / 256;
    int nb_m = (M + 255) / 256;
    int nb_e = (E + 255) / 256;
    float invE = 1.0f / (float)E;

    k_sums<<<1024,256,0,stream>>>(ea, q, E);
    k_prep<<<1,64,0,stream>>>(W1, as1, ad1, We1, ae1, b1, Wm1, bm1,
                              W2, as2, ad2, We2, ae2, q, invE);
    k_z1<<<nb_m,256,0,stream>>>(ei, ea, x, q, pbuf, z1, E, N);
    k_aggr1<<<nb_m,256,0,stream>>>(ei, x, pbuf, z1, xagg, E, N);
    k_h2<<<nb_n,256,0,stream>>>(xagg, q, h2, hsd2, N);
    k_mlp<<<nb_e,256,0,stream>>>(ei, ea, xagg, Wm1, Wm2, bm2, Wm3, bm3,
                                 Wm4, bm4, q, q, pbuf, (unsigned int*)m2, oute, E);
    k_c2<<<1,64,0,stream>>>(q, invE);
    k_selfm2<<<nb_n,256,0,stream>>>(hsd2, q, (unsigned int*)m2, N);
    k_z2<<<nb_m,256,0,stream>>>(ei, pbuf, hsd2, q, (const unsigned int*)m2, z2, E, N);
    k_aggr2<<<nb_m,256,0,stream>>>(ei, pbuf, hsd2, h2, q, (const unsigned int*)m2, z2, x2a, E, N);
    k_out<<<nb_n,256,0,stream>>>(x2a, b2, outn, N);
}

// Round 16
// 1408.011 us; speedup vs baseline: 3.2283x; 1.4350x over previous
//
#include <hip/hip_runtime.h>
#include <hip/hip_bf16.h>

static __device__ __forceinline__ float lrelu(float v){ return v >= 0.f ? v : 0.2f*v; }

#define FMA4(D_, S_, V_) { D_.x += (S_)*(V_).x; D_.y += (S_)*(V_).y; \
                           D_.z += (S_)*(V_).z; D_.w += (S_)*(V_).w; }

// q slots (256 floats):
// 0..2 sum(ea cols) | 3 sum(et2) | 4..6 g1 | 7 c1 | 8..11 g2 | 12 c2
// 16..19 vs1 | 20..23 vd1 | 28..35 PM | 36..37 Q
// 40..43 S | 44 s0 | 45..48 D | 49 d0
// 64..127 A=W1@Wm1_top | 128..191 B=W1@Wm1_bot | 192..207 bb

__global__ void __launch_bounds__(256)
k_sums(const float* __restrict__ ea, float* __restrict__ q, int E)
{
    float s0 = 0.f, s1 = 0.f, s2 = 0.f;
    int stride = gridDim.x * blockDim.x;
    for (int e = blockIdx.x*blockDim.x + threadIdx.x; e < E; e += stride){
        size_t o = 3*(size_t)e;
        s0 += ea[o]; s1 += ea[o+1]; s2 += ea[o+2];
    }
    for (int o = 32; o > 0; o >>= 1){
        s0 += __shfl_down(s0, o);
        s1 += __shfl_down(s1, o);
        s2 += __shfl_down(s2, o);
    }
    if ((threadIdx.x & 63) == 0){
        atomicAdd(&q[0], s0); atomicAdd(&q[1], s1); atomicAdd(&q[2], s2);
    }
}

__global__ void
k_prep(const float* __restrict__ W1, const float* __restrict__ as1,
       const float* __restrict__ ad1,
       const float* __restrict__ We1, const float* __restrict__ ae1,
       const float* __restrict__ b1,
       const float* __restrict__ Wm1, const float* __restrict__ bm1,
       const float* __restrict__ W2, const float* __restrict__ as2,
       const float* __restrict__ ad2,
       const float* __restrict__ We2, const float* __restrict__ ae2,
       float* __restrict__ q, float invE)
{
    __shared__ float sPM[8], sQ[2];
    int t = threadIdx.x;
    if (t < 16){
        int j = t;
        float a0=0,a1=0,a2=0,a3=0, c0=0,c1v=0,c2v=0,c3=0, tb=0;
        for (int i = 0; i < 16; i++){
            float wt = Wm1[i*16 + j];
            float wb = Wm1[(19+i)*16 + j];
            a0 += W1[0*16+i]*wt; a1 += W1[1*16+i]*wt;
            a2 += W1[2*16+i]*wt; a3 += W1[3*16+i]*wt;
            c0 += W1[0*16+i]*wb; c1v += W1[1*16+i]*wb;
            c2v += W1[2*16+i]*wb; c3 += W1[3*16+i]*wb;
            tb += b1[i]*(wt + wb);
        }
        q[64+0*16+j] = a0; q[64+1*16+j] = a1; q[64+2*16+j] = a2; q[64+3*16+j] = a3;
        q[128+0*16+j] = c0; q[128+1*16+j] = c1v; q[128+2*16+j] = c2v; q[128+3*16+j] = c3;
        q[192+j] = bm1[j] + tb;
    } else if (t < 20){
        int c = t - 16;
        float vs = 0.f, vd = 0.f, p0 = 0.f, p1 = 0.f;
        for (int i = 0; i < 16; i++){
            float w = W1[c*16 + i];
            vs += w * as1[i];
            vd += w * ad1[i];
            p0 += w * W2[i*2 + 0];
            p1 += w * W2[i*2 + 1];
        }
        q[16+c] = vs; q[20+c] = vd;
        q[28+c*2+0] = p0; q[28+c*2+1] = p1;
        sPM[c*2+0] = p0; sPM[c*2+1] = p1;
    } else if (t == 20){
        float c1 = 0.f;
        for (int k = 0; k < 3; k++){
            float g = 0.f;
            for (int j = 0; j < 16; j++) g += We1[k*16 + j] * ae1[j];
            q[4+k] = g;
            c1 += q[k] * invE * g;
        }
        q[7] = c1;
    } else if (t == 21){
        for (int k = 0; k < 4; k++)
            q[8+k] = We2[k*2] * ae2[0] + We2[k*2+1] * ae2[1];
    } else if (t == 22){
        float q0 = 0.f, q1 = 0.f;
        for (int i = 0; i < 16; i++){
            q0 += b1[i] * W2[i*2];
            q1 += b1[i] * W2[i*2+1];
        }
        q[36] = q0; q[37] = q1;
        sQ[0] = q0; sQ[1] = q1;
    }
    __syncthreads();
    if (t == 0){
        float a0 = as2[0], a1 = as2[1], d0 = ad2[0], d1 = ad2[1];
        for (int c = 0; c < 4; c++){
            q[40+c] = sPM[c*2]*a0 + sPM[c*2+1]*a1;
            q[45+c] = sPM[c*2]*d0 + sPM[c*2+1]*d1;
        }
        q[44] = sQ[0]*a0 + sQ[1]*a1;
        q[49] = sQ[0]*d0 + sQ[1]*d1;
    }
}

// ---------- CSR build ----------
__global__ void __launch_bounds__(256)
k_hist(const int* __restrict__ ei, unsigned int* __restrict__ ofs, int E)
{
    int e = blockIdx.x*256 + threadIdx.x;
    if (e >= E) return;
    atomicAdd(&ofs[ei[E + e]], 1u);
}

__global__ void __launch_bounds__(256)
k_scan1(const unsigned int* __restrict__ cnt, unsigned int* __restrict__ rowptr,
        unsigned int* __restrict__ aux, int N)
{
    __shared__ unsigned int s[256];
    int t = threadIdx.x;
    int i = blockIdx.x*256 + t;
    unsigned int v = (i < N) ? cnt[i] : 0u;
    s[t] = v;
    __syncthreads();
    for (int off = 1; off < 256; off <<= 1){
        unsigned int add = (t >= off) ? s[t-off] : 0u;
        __syncthreads();
        s[t] += add;
        __syncthreads();
    }
    if (i < N) rowptr[i] = s[t] - v;       // exclusive
    if (t == 255) aux[blockIdx.x] = s[t];  // block total
}

__global__ void __launch_bounds__(1024)
k_scan2(unsigned int* __restrict__ aux, int nbs)
{
    __shared__ unsigned int s[1024];
    int t = threadIdx.x;
    unsigned int v = (t < nbs) ? aux[t] : 0u;
    s[t] = v;
    __syncthreads();
    for (int off = 1; off < 1024; off <<= 1){
        unsigned int add = (t >= off) ? s[t-off] : 0u;
        __syncthreads();
        s[t] += add;
        __syncthreads();
    }
    if (t < nbs) aux[t] = s[t] - v;        // exclusive block offsets
}

__global__ void __launch_bounds__(256)
k_scan3(unsigned int* __restrict__ rowptr, unsigned int* __restrict__ ofs,
        const unsigned int* __restrict__ aux, int N)
{
    int i = blockIdx.x*256 + threadIdx.x;
    if (i >= N) return;
    unsigned int r = rowptr[i] + aux[blockIdx.x];
    rowptr[i] = r;
    ofs[i] = r;   // running insert pointer for scatter
}

__global__ void __launch_bounds__(256)
k_scatter(const int* __restrict__ ei, const float* __restrict__ ea,
          const float* __restrict__ q, unsigned int* __restrict__ ofs,
          float2* __restrict__ sg, float* oute, int E)
{
    int e = blockIdx.x*256 + threadIdx.x;
    if (e >= E) return;
    int s = ei[e], d = ei[E + e];
    size_t o = 3*(size_t)e;
    float ge = ea[o]*q[4] + ea[o+1]*q[5] + ea[o+2]*q[6];
    unsigned int pos = atomicAdd(&ofs[d], 1u);
    float2 r;
    r.x = __int_as_float(s);
    r.y = ge;
    sg[pos] = r;
    ((int*)oute)[4*(size_t)e] = (int)pos;   // stash sorted slot in own oute lane
}

// ---------- layer 1: gather, no atomics ----------
__global__ void __launch_bounds__(256)
k_l1(const unsigned int* __restrict__ rowptr, const unsigned int* __restrict__ ofs,
     const float2* __restrict__ sg, const float* __restrict__ x,
     const float* __restrict__ q, float* __restrict__ xagg, int N)
{
    __shared__ float sq[32];
    if (threadIdx.x < 32) sq[threadIdx.x] = q[threadIdx.x];
    __syncthreads();
    int d = blockIdx.x*256 + threadIdx.x;
    if (d >= N) return;
    float4 xd = ((const float4*)x)[d];
    float hd = xd.x*sq[20] + xd.y*sq[21] + xd.z*sq[22] + xd.w*sq[23];
    float hs_self = xd.x*sq[16] + xd.y*sq[17] + xd.z*sq[18] + xd.w*sq[19];
    float a = hs_self + hd + sq[7];
    float p = expf(fminf(lrelu(a), 60.0f));
    float z = p;
    float4 acc;
    acc.x = p*xd.x; acc.y = p*xd.y; acc.z = p*xd.z; acc.w = p*xd.w;
    unsigned int beg = rowptr[d], end = ofs[d];
    for (unsigned int j = beg; j < end; j++){
        float2 r = sg[j];
        int s = __float_as_int(r.x);
        float4 xs = ((const float4*)x)[s];
        float av = xs.x*sq[16] + xs.y*sq[17] + xs.z*sq[18] + xs.w*sq[19] + hd + r.y;
        float pv = expf(fminf(lrelu(av), 60.0f));
        z += pv;
        FMA4(acc, pv, xs);
    }
    float inv = 1.0f / z;
    acc.x *= inv; acc.y *= inv; acc.z *= inv; acc.w *= inv;
    ((float4*)xagg)[d] = acc;
}

// ---------- edge MLP (edge order) ----------
__global__ void __launch_bounds__(256)
k_mlp(const int* __restrict__ ei, const float* __restrict__ ea,
      const float* __restrict__ xagg,
      const float* __restrict__ Wm1, const float* __restrict__ Wm2,
      const float* __restrict__ bm2, const float* __restrict__ Wm3,
      const float* __restrict__ bm3, const float* __restrict__ Wm4,
      const float* __restrict__ bm4,
      const float* __restrict__ q, float* __restrict__ qw,
      float2* __restrict__ sg, float* oute, int E)
{
    __shared__ __align__(16) float L[656];
    __shared__ float R[256];
    for (int t = threadIdx.x; t < 656; t += 256){
        float v;
        if      (t < 128)  v = q[64 + t];           // A then B
        else if (t < 144)  v = q[192 + (t-128)];    // bb
        else if (t < 192)  v = Wm1[256 + (t-144)];  // C3 = Wm1 rows 16..18
        else if (t < 448)  v = Wm2[t-192];
        else if (t < 464)  v = bm2[t-448];
        else if (t < 592)  v = Wm3[t-464];
        else if (t < 600)  v = bm3[t-592];
        else if (t < 632)  v = Wm4[t-600];
        else if (t < 636)  v = bm4[t-632];
        else if (t < 640)  v = q[8 + (t-636)];      // g2
        else               v = q[40 + (t-640)];     // S,s0,D,d0
        L[t] = v;
    }
    __syncthreads();
    const float4* A4  = (const float4*)(L);
    const float4* B4  = (const float4*)(L + 64);
    const float4* bb4 = (const float4*)(L + 128);
    const float4* C34 = (const float4*)(L + 144);
    const float4* W24 = (const float4*)(L + 192);
    const float4* B24 = (const float4*)(L + 448);
    const float4* W34 = (const float4*)(L + 464);
    const float4* B34 = (const float4*)(L + 592);
    const float4* W44 = (const float4*)(L + 600);
    const float*  sg2v = L + 636;
    const float*  SD  = L + 640;

    int e = blockIdx.x*256 + threadIdx.x;
    float et = 0.f;
    if (e < E){
        int sp = ((const int*)oute)[4*(size_t)e];   // read own stash BEFORE overwrite
        int si = ei[e], di = ei[E+e];
        float4 xs = ((const float4*)xagg)[si];
        float4 xd = ((const float4*)xagg)[di];
        size_t eo = 3*(size_t)e;
        float e0 = ea[eo], e1 = ea[eo+1], e2v = ea[eo+2];

        float u1[16];
        #pragma unroll
        for (int j4 = 0; j4 < 4; j4++){
            float4 acc = bb4[j4];
            FMA4(acc, xs.x, A4[0*4+j4]); FMA4(acc, xs.y, A4[1*4+j4]);
            FMA4(acc, xs.z, A4[2*4+j4]); FMA4(acc, xs.w, A4[3*4+j4]);
            FMA4(acc, e0, C34[0*4+j4]); FMA4(acc, e1, C34[1*4+j4]);
            FMA4(acc, e2v, C34[2*4+j4]);
            FMA4(acc, xd.x, B4[0*4+j4]); FMA4(acc, xd.y, B4[1*4+j4]);
            FMA4(acc, xd.z, B4[2*4+j4]); FMA4(acc, xd.w, B4[3*4+j4]);
            u1[j4*4+0] = fmaxf(acc.x, 0.f);
            u1[j4*4+1] = fmaxf(acc.y, 0.f);
            u1[j4*4+2] = fmaxf(acc.z, 0.f);
            u1[j4*4+3] = fmaxf(acc.w, 0.f);
        }

        float4 v0 = B24[0], v1 = B24[1], v2 = B24[2], v3 = B24[3];
        #pragma unroll
        for (int c = 0; c < 16; c++){
            float uc = u1[c];
            FMA4(v0, uc, W24[c*4+0]);
            FMA4(v1, uc, W24[c*4+1]);
            FMA4(v2, uc, W24[c*4+2]);
            FMA4(v3, uc, W24[c*4+3]);
        }
        float u2[16];
        u2[0]=fmaxf(v0.x,0.f); u2[1]=fmaxf(v0.y,0.f); u2[2]=fmaxf(v0.z,0.f); u2[3]=fmaxf(v0.w,0.f);
        u2[4]=fmaxf(v1.x,0.f); u2[5]=fmaxf(v1.y,0.f); u2[6]=fmaxf(v1.z,0.f); u2[7]=fmaxf(v1.w,0.f);
        u2[8]=fmaxf(v2.x,0.f); u2[9]=fmaxf(v2.y,0.f); u2[10]=fmaxf(v2.z,0.f); u2[11]=fmaxf(v2.w,0.f);
        u2[12]=fmaxf(v3.x,0.f); u2[13]=fmaxf(v3.y,0.f); u2[14]=fmaxf(v3.z,0.f); u2[15]=fmaxf(v3.w,0.f);

        float4 w0 = B34[0], w1 = B34[1];
        #pragma unroll
        for (int c = 0; c < 16; c++){
            float uc = u2[c];
            FMA4(w0, uc, W34[c*2+0]);
            FMA4(w1, uc, W34[c*2+1]);
        }
        float u3[8];
        u3[0]=fmaxf(w0.x,0.f); u3[1]=fmaxf(w0.y,0.f); u3[2]=fmaxf(w0.z,0.f); u3[3]=fmaxf(w0.w,0.f);
        u3[4]=fmaxf(w1.x,0.f); u3[5]=fmaxf(w1.y,0.f); u3[6]=fmaxf(w1.z,0.f); u3[7]=fmaxf(w1.w,0.f);

        float4 ev = *(const float4*)(L + 632);  // bm4
        #pragma unroll
        for (int c = 0; c < 8; c++){
            float uc = u3[c];
            FMA4(ev, uc, W44[c]);
        }

        float mx = fmaxf(fmaxf(ev.x, ev.y), fmaxf(ev.z, ev.w));
        float ls = logf(expf(ev.x-mx)+expf(ev.y-mx)+expf(ev.z-mx)+expf(ev.w-mx)) + mx;
        float4 o;
        o.x = ev.x-ls; o.y = ev.y-ls; o.z = ev.z-ls; o.w = ev.w-ls;
        ((float4*)oute)[e] = o;

        et = ev.x*sg2v[0] + ev.y*sg2v[1] + ev.z*sg2v[2] + ev.w*sg2v[3];
        float hs2 = xs.x*SD[0] + xs.y*SD[1] + xs.z*SD[2] + xs.w*SD[3] + SD[4];
        float hd2 = xd.x*SD[5] + xd.y*SD[6] + xd.z*SD[7] + xd.w*SD[8] + SD[9];
        sg[sp].y = lrelu(hs2 + hd2 + et);   // a2 into sorted slot (overwrites dead ge)
    }
    R[threadIdx.x] = et;
    __syncthreads();
    for (int off = 128; off > 0; off >>= 1){
        if (threadIdx.x < off) R[threadIdx.x] += R[threadIdx.x + off];
        __syncthreads();
    }
    if (threadIdx.x == 0) atomicAdd(&qw[3], R[0]);
}

__global__ void
k_c2(float* __restrict__ q, float invE)
{
    if (threadIdx.x == 0 && blockIdx.x == 0) q[12] = q[3] * invE;
}

// ---------- layer 2: gather, exact max, fused output ----------
__global__ void __launch_bounds__(256)
k_l2(const unsigned int* __restrict__ rowptr, const unsigned int* __restrict__ ofs,
     const float2* __restrict__ sg, const float* __restrict__ xagg,
     const float* __restrict__ q, const float* __restrict__ b2,
     float* __restrict__ outn, int N)
{
    __shared__ float sq[64];
    if (threadIdx.x < 64) sq[threadIdx.x] = q[threadIdx.x];
    __syncthreads();
    int d = blockIdx.x*256 + threadIdx.x;
    if (d >= N) return;
    float4 xa = ((const float4*)xagg)[d];
    float h2d0 = xa.x*sq[28] + xa.y*sq[30] + xa.z*sq[32] + xa.w*sq[34] + sq[36];
    float h2d1 = xa.x*sq[29] + xa.y*sq[31] + xa.z*sq[33] + xa.w*sq[35] + sq[37];
    float hs2 = xa.x*sq[40] + xa.y*sq[41] + xa.z*sq[42] + xa.w*sq[43] + sq[44];
    float hd2 = xa.x*sq[45] + xa.y*sq[46] + xa.z*sq[47] + xa.w*sq[48] + sq[49];
    float aself = lrelu(hs2 + hd2 + sq[12]);
    unsigned int beg = rowptr[d], end = ofs[d];
    float m = aself;
    for (unsigned int j = beg; j < end; j++)
        m = fmaxf(m, sg[j].y);
    float z = expf(aself - m);
    float acc0 = z*h2d0, acc1 = z*h2d1;
    for (unsigned int j = beg; j < end; j++){
        float2 r = sg[j];
        int s = __float_as_int(r.x);
        float p = expf(r.y - m);
        z += p;
        float4 xs = ((const float4*)xagg)[s];
        float h0 = xs.x*sq[28] + xs.y*sq[30] + xs.z*sq[32] + xs.w*sq[34] + sq[36];
        float h1 = xs.x*sq[29] + xs.y*sq[31] + xs.z*sq[33] + xs.w*sq[35] + sq[37];
        acc0 += p*h0;
        acc1 += p*h1;
    }
    float inv = 1.0f / z;
    float v0 = acc0*inv + b2[0];
    float v1 = acc1*inv + b2[1];
    float mm = fmaxf(v0, v1);
    float ls = logf(expf(v0-mm) + expf(v1-mm)) + mm;
    float2 o;
    o.x = v0 - ls;
    o.y = v1 - ls;
    ((float2*)outn)[d] = o;
}

extern "C" void kernel_launch(void* const* d_in, const int* in_sizes, int n_in,
                              void* d_out, int out_size, void* d_ws, size_t ws_size,
                              hipStream_t stream)
{
    const float* x   = (const float*)d_in[0];
    const int*   ei  = (const int*)  d_in[1];
    const float* ea  = (const float*)d_in[2];
    const float* W1  = (const float*)d_in[3];
    const float* as1 = (const float*)d_in[4];
    const float* ad1 = (const float*)d_in[5];
    const float* We1 = (const float*)d_in[6];
    const float* ae1 = (const float*)d_in[7];
    const float* b1  = (const float*)d_in[8];
    const float* Wm1 = (const float*)d_in[9];
    const float* bm1 = (const float*)d_in[10];
    const float* Wm2 = (const float*)d_in[11];
    const float* bm2 = (const float*)d_in[12];
    const float* Wm3 = (const float*)d_in[13];
    const float* bm3 = (const float*)d_in[14];
    const float* Wm4 = (const float*)d_in[15];
    const float* bm4 = (const float*)d_in[16];
    const float* W2  = (const float*)d_in[17];
    const float* as2 = (const float*)d_in[18];
    const float* ad2 = (const float*)d_in[19];
    const float* We2 = (const float*)d_in[20];
    const float* ae2 = (const float*)d_in[21];
    const float* b2  = (const float*)d_in[22];

    const int N = in_sizes[0] / 4;
    const int E = in_sizes[1] / 2;

    int nb_n = (N + 255) / 256;
    int nb_e = (E + 255) / 256;
    if (nb_n > 1024) return;   // scan2 capacity (N <= 262144; here N=200000)

    // ws: q(256) | ofs(N u32) | rowptr(N u32) | aux(1024 u32) | xagg(4N) | sg(2E)
    size_t needFloats = 256 + 2*(size_t)N + 1024 + 4*(size_t)N + 2*(size_t)E;
    if (ws_size < needFloats*sizeof(float)) return;

    float* ws = (float*)d_ws;
    float* q  = ws;
    unsigned int* ofs    = (unsigned int*)(ws + 256);
    unsigned int* rowptr = ofs + N;
    unsigned int* aux    = rowptr + N;
    float* xagg = ws + 256 + 2*(size_t)N + 1024;
    float2* sg  = (float2*)(xagg + 4*(size_t)N);

    // zero q + ofs only (rowptr/aux/xagg/sg fully written)
    hipMemsetAsync(d_ws, 0, (256 + (size_t)N)*sizeof(float), stream);

    float* outn = (float*)d_out;
    float* oute = outn + 2*(size_t)N;

    float invE = 1.0f / (float)E;

    k_sums<<<1024,256,0,stream>>>(ea, q, E);
    k_prep<<<1,64,0,stream>>>(W1, as1, ad1, We1, ae1, b1, Wm1, bm1,
                              W2, as2, ad2, We2, ae2, q, invE);
    k_hist<<<nb_e,256,0,stream>>>(ei, ofs, E);
    k_scan1<<<nb_n,256,0,stream>>>(ofs, rowptr, aux, N);
    k_scan2<<<1,1024,0,stream>>>(aux, nb_n);
    k_scan3<<<nb_n,256,0,stream>>>(rowptr, ofs, aux, N);
    k_scatter<<<nb_e,256,0,stream>>>(ei, ea, q, ofs, sg, oute, E);
    k_l1<<<nb_n,256,0,stream>>>(rowptr, ofs, sg, x, q, xagg, N);
    k_mlp<<<nb_e,256,0,stream>>>(ei, ea, xagg, Wm1, Wm2, bm2, Wm3, bm3,
                                 Wm4, bm4, q, q, sg, oute, E);
    k_c2<<<1,64,0,stream>>>(q, invE);
    k_l2<<<nb_n,256,0,stream>>>(rowptr, ofs, sg, xagg, q, b2, outn, N);
}

// Round 17
// 903.797 us; speedup vs baseline: 5.0293x; 1.5579x over previous
//
#include <hip/hip_runtime.h>
#include <hip/hip_bf16.h>

static __device__ __forceinline__ float lrelu(float v){ return v >= 0.f ? v : 0.2f*v; }

#define FMA4(D_, S_, V_) { D_.x += (S_)*(V_).x; D_.y += (S_)*(V_).y; \
                           D_.z += (S_)*(V_).z; D_.w += (S_)*(V_).w; }

// q slots (256 floats):
// 0..2 sum(ea cols) | 3 sum(et2) | 4..6 g1 | 7 c1 | 8..11 g2 | 12 c2
// 16..19 vs1 | 20..23 vd1 | 28..35 PM | 36..37 Q
// 40..43 S | 44 s0 | 45..48 D | 49 d0
// 64..127 A=W1@Wm1_top | 128..191 B=W1@Wm1_bot | 192..207 bb

__global__ void __launch_bounds__(256)
k_sums(const float* __restrict__ ea, float* __restrict__ q, int E)
{
    float s0 = 0.f, s1 = 0.f, s2 = 0.f;
    int stride = gridDim.x * blockDim.x;
    for (int e = blockIdx.x*blockDim.x + threadIdx.x; e < E; e += stride){
        size_t o = 3*(size_t)e;
        s0 += ea[o]; s1 += ea[o+1]; s2 += ea[o+2];
    }
    for (int o = 32; o > 0; o >>= 1){
        s0 += __shfl_down(s0, o);
        s1 += __shfl_down(s1, o);
        s2 += __shfl_down(s2, o);
    }
    if ((threadIdx.x & 63) == 0){
        atomicAdd(&q[0], s0); atomicAdd(&q[1], s1); atomicAdd(&q[2], s2);
    }
}

__global__ void
k_prep(const float* __restrict__ W1, const float* __restrict__ as1,
       const float* __restrict__ ad1,
       const float* __restrict__ We1, const float* __restrict__ ae1,
       const float* __restrict__ b1,
       const float* __restrict__ Wm1, const float* __restrict__ bm1,
       const float* __restrict__ W2, const float* __restrict__ as2,
       const float* __restrict__ ad2,
       const float* __restrict__ We2, const float* __restrict__ ae2,
       float* __restrict__ q, float invE)
{
    __shared__ float sPM[8], sQ[2];
    int t = threadIdx.x;
    if (t < 16){
        int j = t;
        float a0=0,a1=0,a2=0,a3=0, c0=0,c1v=0,c2v=0,c3=0, tb=0;
        for (int i = 0; i < 16; i++){
            float wt = Wm1[i*16 + j];
            float wb = Wm1[(19+i)*16 + j];
            a0 += W1[0*16+i]*wt; a1 += W1[1*16+i]*wt;
            a2 += W1[2*16+i]*wt; a3 += W1[3*16+i]*wt;
            c0 += W1[0*16+i]*wb; c1v += W1[1*16+i]*wb;
            c2v += W1[2*16+i]*wb; c3 += W1[3*16+i]*wb;
            tb += b1[i]*(wt + wb);
        }
        q[64+0*16+j] = a0; q[64+1*16+j] = a1; q[64+2*16+j] = a2; q[64+3*16+j] = a3;
        q[128+0*16+j] = c0; q[128+1*16+j] = c1v; q[128+2*16+j] = c2v; q[128+3*16+j] = c3;
        q[192+j] = bm1[j] + tb;
    } else if (t < 20){
        int c = t - 16;
        float vs = 0.f, vd = 0.f, p0 = 0.f, p1 = 0.f;
        for (int i = 0; i < 16; i++){
            float w = W1[c*16 + i];
            vs += w * as1[i];
            vd += w * ad1[i];
            p0 += w * W2[i*2 + 0];
            p1 += w * W2[i*2 + 1];
        }
        q[16+c] = vs; q[20+c] = vd;
        q[28+c*2+0] = p0; q[28+c*2+1] = p1;
        sPM[c*2+0] = p0; sPM[c*2+1] = p1;
    } else if (t == 20){
        float c1 = 0.f;
        for (int k = 0; k < 3; k++){
            float g = 0.f;
            for (int j = 0; j < 16; j++) g += We1[k*16 + j] * ae1[j];
            q[4+k] = g;
            c1 += q[k] * invE * g;
        }
        q[7] = c1;
    } else if (t == 21){
        for (int k = 0; k < 4; k++)
            q[8+k] = We2[k*2] * ae2[0] + We2[k*2+1] * ae2[1];
    } else if (t == 22){
        float q0 = 0.f, q1 = 0.f;
        for (int i = 0; i < 16; i++){
            q0 += b1[i] * W2[i*2];
            q1 += b1[i] * W2[i*2+1];
        }
        q[36] = q0; q[37] = q1;
        sQ[0] = q0; sQ[1] = q1;
    }
    __syncthreads();
    if (t == 0){
        float a0 = as2[0], a1 = as2[1], d0 = ad2[0], d1 = ad2[1];
        for (int c = 0; c < 4; c++){
            q[40+c] = sPM[c*2]*a0 + sPM[c*2+1]*a1;
            q[45+c] = sPM[c*2]*d0 + sPM[c*2+1]*d1;
        }
        q[44] = sQ[0]*a0 + sQ[1]*a1;
        q[49] = sQ[0]*d0 + sQ[1]*d1;
    }
}

// ---------- CSR build ----------
__global__ void __launch_bounds__(256)
k_hist(const int* __restrict__ ei, unsigned int* __restrict__ ofs, int E)
{
    int e = blockIdx.x*256 + threadIdx.x;
    if (e >= E) return;
    atomicAdd(&ofs[ei[E + e]], 1u);
}

__global__ void __launch_bounds__(256)
k_scan1(const unsigned int* __restrict__ cnt, unsigned int* __restrict__ rowptr,
        unsigned int* __restrict__ aux, int N)
{
    __shared__ unsigned int s[256];
    int t = threadIdx.x;
    int i = blockIdx.x*256 + t;
    unsigned int v = (i < N) ? cnt[i] : 0u;
    s[t] = v;
    __syncthreads();
    for (int off = 1; off < 256; off <<= 1){
        unsigned int add = (t >= off) ? s[t-off] : 0u;
        __syncthreads();
        s[t] += add;
        __syncthreads();
    }
    if (i < N) rowptr[i] = s[t] - v;
    if (t == 255) aux[blockIdx.x] = s[t];
}

__global__ void __launch_bounds__(1024)
k_scan2(unsigned int* __restrict__ aux, int nbs)
{
    __shared__ unsigned int s[1024];
    int t = threadIdx.x;
    unsigned int v = (t < nbs) ? aux[t] : 0u;
    s[t] = v;
    __syncthreads();
    for (int off = 1; off < 1024; off <<= 1){
        unsigned int add = (t >= off) ? s[t-off] : 0u;
        __syncthreads();
        s[t] += add;
        __syncthreads();
    }
    if (t < nbs) aux[t] = s[t] - v;
}

__global__ void __launch_bounds__(256)
k_scan3(unsigned int* __restrict__ rowptr, unsigned int* __restrict__ ofs,
        const unsigned int* __restrict__ aux, int N)
{
    int i = blockIdx.x*256 + threadIdx.x;
    if (i >= N) return;
    unsigned int r = rowptr[i] + aux[blockIdx.x];
    rowptr[i] = r;
    ofs[i] = r;
}

__global__ void __launch_bounds__(256)
k_scatter(const int* __restrict__ ei, const float* __restrict__ ea,
          const float* __restrict__ q, unsigned int* __restrict__ ofs,
          float2* __restrict__ sg, float* oute, int E)
{
    int e = blockIdx.x*256 + threadIdx.x;
    if (e >= E) return;
    int s = ei[e], d = ei[E + e];
    size_t o = 3*(size_t)e;
    float ge = ea[o]*q[4] + ea[o+1]*q[5] + ea[o+2]*q[6];
    unsigned int pos = atomicAdd(&ofs[d], 1u);
    float2 r;
    r.x = __int_as_float(s);
    r.y = ge;
    sg[pos] = r;
    ((int*)oute)[4*(size_t)e] = (int)pos;
}

// ---------- layer 1: gather, no atomics ----------
__global__ void __launch_bounds__(256)
k_l1(const unsigned int* __restrict__ rowptr, const unsigned int* __restrict__ ofs,
     const float2* __restrict__ sg, const float* __restrict__ x,
     const float* __restrict__ q, float* __restrict__ xagg, int N)
{
    __shared__ float sq[32];
    if (threadIdx.x < 32) sq[threadIdx.x] = q[threadIdx.x];
    __syncthreads();
    int d = blockIdx.x*256 + threadIdx.x;
    if (d >= N) return;
    float4 xd = ((const float4*)x)[d];
    float hd = xd.x*sq[20] + xd.y*sq[21] + xd.z*sq[22] + xd.w*sq[23];
    float hs_self = xd.x*sq[16] + xd.y*sq[17] + xd.z*sq[18] + xd.w*sq[19];
    float a = hs_self + hd + sq[7];
    float p = expf(fminf(lrelu(a), 60.0f));
    float z = p;
    float4 acc;
    acc.x = p*xd.x; acc.y = p*xd.y; acc.z = p*xd.z; acc.w = p*xd.w;
    unsigned int beg = rowptr[d], end = ofs[d];
    for (unsigned int j = beg; j < end; j++){
        float2 r = sg[j];
        int s = __float_as_int(r.x);
        float4 xs = ((const float4*)x)[s];
        float av = xs.x*sq[16] + xs.y*sq[17] + xs.z*sq[18] + xs.w*sq[19] + hd + r.y;
        float pv = expf(fminf(lrelu(av), 60.0f));
        z += pv;
        FMA4(acc, pv, xs);
    }
    float inv = 1.0f / z;
    acc.x *= inv; acc.y *= inv; acc.z *= inv; acc.w *= inv;
    ((float4*)xagg)[d] = acc;
}

// ---------- edge MLP: 4 edges per thread ----------
__global__ void __launch_bounds__(256)
k_mlp(const int* __restrict__ ei, const float* __restrict__ ea,
      const float* __restrict__ xagg,
      const float* __restrict__ Wm1, const float* __restrict__ Wm2,
      const float* __restrict__ bm2, const float* __restrict__ Wm3,
      const float* __restrict__ bm3, const float* __restrict__ Wm4,
      const float* __restrict__ bm4,
      const float* __restrict__ q, float* __restrict__ qw,
      float2* __restrict__ sg, float* oute, int E)
{
    __shared__ __align__(16) float L[656];
    __shared__ float R[256];
    for (int t = threadIdx.x; t < 656; t += 256){
        float v;
        if      (t < 128)  v = q[64 + t];
        else if (t < 144)  v = q[192 + (t-128)];
        else if (t < 192)  v = Wm1[256 + (t-144)];
        else if (t < 448)  v = Wm2[t-192];
        else if (t < 464)  v = bm2[t-448];
        else if (t < 592)  v = Wm3[t-464];
        else if (t < 600)  v = bm3[t-592];
        else if (t < 632)  v = Wm4[t-600];
        else if (t < 636)  v = bm4[t-632];
        else if (t < 640)  v = q[8 + (t-636)];
        else               v = q[40 + (t-640)];
        L[t] = v;
    }
    __syncthreads();
    const float4* A4  = (const float4*)(L);
    const float4* B4  = (const float4*)(L + 64);
    const float4* bb4 = (const float4*)(L + 128);
    const float4* C34 = (const float4*)(L + 144);
    const float4* W24 = (const float4*)(L + 192);
    const float4* B24 = (const float4*)(L + 448);
    const float4* W34 = (const float4*)(L + 464);
    const float4* B34 = (const float4*)(L + 592);
    const float4* W44 = (const float4*)(L + 600);
    const float*  sg2v = L + 636;
    const float*  SD  = L + 640;

    int tg = blockIdx.x*256 + threadIdx.x;
    int e0 = tg*4;
    float etsum = 0.f;
    if (e0 + 3 < E){
        int4 sis = ((const int4*)ei)[tg];
        int4 dis = ((const int4*)(ei + E))[tg];
        int si[4] = { sis.x, sis.y, sis.z, sis.w };
        int di[4] = { dis.x, dis.y, dis.z, dis.w };
        float4 eA = ((const float4*)ea)[3*tg+0];
        float4 eB = ((const float4*)ea)[3*tg+1];
        float4 eC = ((const float4*)ea)[3*tg+2];
        float eaf[4][3] = {
            { eA.x, eA.y, eA.z },
            { eA.w, eB.x, eB.y },
            { eB.z, eB.w, eC.x },
            { eC.y, eC.z, eC.w }
        };
        int stash[4];
        #pragma unroll
        for (int k = 0; k < 4; k++)
            stash[k] = ((const int*)oute)[4*(size_t)(e0+k)];

        float xsf[4][4], xdf[4][4], hsd[4];
        #pragma unroll
        for (int k = 0; k < 4; k++){
            float4 xs = ((const float4*)xagg)[si[k]];
            float4 xd = ((const float4*)xagg)[di[k]];
            xsf[k][0]=xs.x; xsf[k][1]=xs.y; xsf[k][2]=xs.z; xsf[k][3]=xs.w;
            xdf[k][0]=xd.x; xdf[k][1]=xd.y; xdf[k][2]=xd.z; xdf[k][3]=xd.w;
            float hs2 = xs.x*SD[0] + xs.y*SD[1] + xs.z*SD[2] + xs.w*SD[3] + SD[4];
            float hd2 = xd.x*SD[5] + xd.y*SD[6] + xd.z*SD[7] + xd.w*SD[8] + SD[9];
            hsd[k] = hs2 + hd2;
        }

        // layer 1: 11 inputs -> 16, 4 edges
        float u1[4][16];
        #pragma unroll
        for (int j4 = 0; j4 < 4; j4++){
            float4 acc0 = bb4[j4], acc1 = acc0, acc2 = acc0, acc3 = acc0;
            #pragma unroll
            for (int r = 0; r < 4; r++){
                float4 w = A4[r*4 + j4];
                FMA4(acc0, xsf[0][r], w); FMA4(acc1, xsf[1][r], w);
                FMA4(acc2, xsf[2][r], w); FMA4(acc3, xsf[3][r], w);
            }
            #pragma unroll
            for (int r = 0; r < 3; r++){
                float4 w = C34[r*4 + j4];
                FMA4(acc0, eaf[0][r], w); FMA4(acc1, eaf[1][r], w);
                FMA4(acc2, eaf[2][r], w); FMA4(acc3, eaf[3][r], w);
            }
            #pragma unroll
            for (int r = 0; r < 4; r++){
                float4 w = B4[r*4 + j4];
                FMA4(acc0, xdf[0][r], w); FMA4(acc1, xdf[1][r], w);
                FMA4(acc2, xdf[2][r], w); FMA4(acc3, xdf[3][r], w);
            }
            u1[0][j4*4+0]=fmaxf(acc0.x,0.f); u1[0][j4*4+1]=fmaxf(acc0.y,0.f);
            u1[0][j4*4+2]=fmaxf(acc0.z,0.f); u1[0][j4*4+3]=fmaxf(acc0.w,0.f);
            u1[1][j4*4+0]=fmaxf(acc1.x,0.f); u1[1][j4*4+1]=fmaxf(acc1.y,0.f);
            u1[1][j4*4+2]=fmaxf(acc1.z,0.f); u1[1][j4*4+3]=fmaxf(acc1.w,0.f);
            u1[2][j4*4+0]=fmaxf(acc2.x,0.f); u1[2][j4*4+1]=fmaxf(acc2.y,0.f);
            u1[2][j4*4+2]=fmaxf(acc2.z,0.f); u1[2][j4*4+3]=fmaxf(acc2.w,0.f);
            u1[3][j4*4+0]=fmaxf(acc3.x,0.f); u1[3][j4*4+1]=fmaxf(acc3.y,0.f);
            u1[3][j4*4+2]=fmaxf(acc3.z,0.f); u1[3][j4*4+3]=fmaxf(acc3.w,0.f);
        }

        // layer 2: 16 -> 16
        float u2[4][16];
        #pragma unroll
        for (int j4 = 0; j4 < 4; j4++){
            float4 acc0 = B24[j4], acc1 = acc0, acc2 = acc0, acc3 = acc0;
            #pragma unroll
            for (int c = 0; c < 16; c++){
                float4 w = W24[c*4 + j4];
                FMA4(acc0, u1[0][c], w); FMA4(acc1, u1[1][c], w);
                FMA4(acc2, u1[2][c], w); FMA4(acc3, u1[3][c], w);
            }
            u2[0][j4*4+0]=fmaxf(acc0.x,0.f); u2[0][j4*4+1]=fmaxf(acc0.y,0.f);
            u2[0][j4*4+2]=fmaxf(acc0.z,0.f); u2[0][j4*4+3]=fmaxf(acc0.w,0.f);
            u2[1][j4*4+0]=fmaxf(acc1.x,0.f); u2[1][j4*4+1]=fmaxf(acc1.y,0.f);
            u2[1][j4*4+2]=fmaxf(acc1.z,0.f); u2[1][j4*4+3]=fmaxf(acc1.w,0.f);
            u2[2][j4*4+0]=fmaxf(acc2.x,0.f); u2[2][j4*4+1]=fmaxf(acc2.y,0.f);
            u2[2][j4*4+2]=fmaxf(acc2.z,0.f); u2[2][j4*4+3]=fmaxf(acc2.w,0.f);
            u2[3][j4*4+0]=fmaxf(acc3.x,0.f); u2[3][j4*4+1]=fmaxf(acc3.y,0.f);
            u2[3][j4*4+2]=fmaxf(acc3.z,0.f); u2[3][j4*4+3]=fmaxf(acc3.w,0.f);
        }

        // layer 3: 16 -> 8
        float u3[4][8];
        #pragma unroll
        for (int j2 = 0; j2 < 2; j2++){
            float4 acc0 = B34[j2], acc1 = acc0, acc2 = acc0, acc3 = acc0;
            #pragma unroll
            for (int c = 0; c < 16; c++){
                float4 w = W34[c*2 + j2];
                FMA4(acc0, u2[0][c], w); FMA4(acc1, u2[1][c], w);
                FMA4(acc2, u2[2][c], w); FMA4(acc3, u2[3][c], w);
            }
            u3[0][j2*4+0]=fmaxf(acc0.x,0.f); u3[0][j2*4+1]=fmaxf(acc0.y,0.f);
            u3[0][j2*4+2]=fmaxf(acc0.z,0.f); u3[0][j2*4+3]=fmaxf(acc0.w,0.f);
            u3[1][j2*4+0]=fmaxf(acc1.x,0.f); u3[1][j2*4+1]=fmaxf(acc1.y,0.f);
            u3[1][j2*4+2]=fmaxf(acc1.z,0.f); u3[1][j2*4+3]=fmaxf(acc1.w,0.f);
            u3[2][j2*4+0]=fmaxf(acc2.x,0.f); u3[2][j2*4+1]=fmaxf(acc2.y,0.f);
            u3[2][j2*4+2]=fmaxf(acc2.z,0.f); u3[2][j2*4+3]=fmaxf(acc2.w,0.f);
            u3[3][j2*4+0]=fmaxf(acc3.x,0.f); u3[3][j2*4+1]=fmaxf(acc3.y,0.f);
            u3[3][j2*4+2]=fmaxf(acc3.z,0.f); u3[3][j2*4+3]=fmaxf(acc3.w,0.f);
        }

        // layer 4: 8 -> 4
        float4 ev[4];
        {
            float4 b4v = *(const float4*)(L + 632);
            ev[0] = b4v; ev[1] = b4v; ev[2] = b4v; ev[3] = b4v;
            #pragma unroll
            for (int c = 0; c < 8; c++){
                float4 w = W44[c];
                FMA4(ev[0], u3[0][c], w); FMA4(ev[1], u3[1][c], w);
                FMA4(ev[2], u3[2][c], w); FMA4(ev[3], u3[3][c], w);
            }
        }

        #pragma unroll
        for (int k = 0; k < 4; k++){
            float4 e4 = ev[k];
            float mx = fmaxf(fmaxf(e4.x, e4.y), fmaxf(e4.z, e4.w));
            float ls = logf(expf(e4.x-mx)+expf(e4.y-mx)+expf(e4.z-mx)+expf(e4.w-mx)) + mx;
            float4 o;
            o.x = e4.x-ls; o.y = e4.y-ls; o.z = e4.z-ls; o.w = e4.w-ls;
            ((float4*)oute)[e0+k] = o;
            float et = e4.x*sg2v[0] + e4.y*sg2v[1] + e4.z*sg2v[2] + e4.w*sg2v[3];
            etsum += et;
            sg[stash[k]].y = lrelu(hsd[k] + et);
        }
    } else if (e0 < E){
        // scalar tail (only if E % 4 != 0)
        for (int e = e0; e < E; e++){
            int sp = ((const int*)oute)[4*(size_t)e];
            int si = ei[e], di = ei[E+e];
            float4 xs = ((const float4*)xagg)[si];
            float4 xd = ((const float4*)xagg)[di];
            size_t eo = 3*(size_t)e;
            float e0v = ea[eo], e1v = ea[eo+1], e2v = ea[eo+2];
            float u1s[16];
            #pragma unroll
            for (int j4 = 0; j4 < 4; j4++){
                float4 acc = bb4[j4];
                FMA4(acc, xs.x, A4[0*4+j4]); FMA4(acc, xs.y, A4[1*4+j4]);
                FMA4(acc, xs.z, A4[2*4+j4]); FMA4(acc, xs.w, A4[3*4+j4]);
                FMA4(acc, e0v, C34[0*4+j4]); FMA4(acc, e1v, C34[1*4+j4]);
                FMA4(acc, e2v, C34[2*4+j4]);
                FMA4(acc, xd.x, B4[0*4+j4]); FMA4(acc, xd.y, B4[1*4+j4]);
                FMA4(acc, xd.z, B4[2*4+j4]); FMA4(acc, xd.w, B4[3*4+j4]);
                u1s[j4*4+0]=fmaxf(acc.x,0.f); u1s[j4*4+1]=fmaxf(acc.y,0.f);
                u1s[j4*4+2]=fmaxf(acc.z,0.f); u1s[j4*4+3]=fmaxf(acc.w,0.f);
            }
            float u2s[16];
            #pragma unroll
            for (int j4 = 0; j4 < 4; j4++){
                float4 acc = B24[j4];
                #pragma unroll
                for (int c = 0; c < 16; c++) FMA4(acc, u1s[c], W24[c*4+j4]);
                u2s[j4*4+0]=fmaxf(acc.x,0.f); u2s[j4*4+1]=fmaxf(acc.y,0.f);
                u2s[j4*4+2]=fmaxf(acc.z,0.f); u2s[j4*4+3]=fmaxf(acc.w,0.f);
            }
            float u3s[8];
            #pragma unroll
            for (int j2 = 0; j2 < 2; j2++){
                float4 acc = B34[j2];
                #pragma unroll
                for (int c = 0; c < 16; c++) FMA4(acc, u2s[c], W34[c*2+j2]);
                u3s[j2*4+0]=fmaxf(acc.x,0.f); u3s[j2*4+1]=fmaxf(acc.y,0.f);
                u3s[j2*4+2]=fmaxf(acc.z,0.f); u3s[j2*4+3]=fmaxf(acc.w,0.f);
            }
            float4 e4 = *(const float4*)(L + 632);
            #pragma unroll
            for (int c = 0; c < 8; c++) FMA4(e4, u3s[c], W44[c]);
            float mx = fmaxf(fmaxf(e4.x, e4.y), fmaxf(e4.z, e4.w));
            float ls = logf(expf(e4.x-mx)+expf(e4.y-mx)+expf(e4.z-mx)+expf(e4.w-mx)) + mx;
            float4 o;
            o.x = e4.x-ls; o.y = e4.y-ls; o.z = e4.z-ls; o.w = e4.w-ls;
            ((float4*)oute)[e] = o;
            float et = e4.x*sg2v[0] + e4.y*sg2v[1] + e4.z*sg2v[2] + e4.w*sg2v[3];
            etsum += et;
            float hs2 = xs.x*SD[0] + xs.y*SD[1] + xs.z*SD[2] + xs.w*SD[3] + SD[4];
            float hd2 = xd.x*SD[5] + xd.y*SD[6] + xd.z*SD[7] + xd.w*SD[8] + SD[9];
            sg[sp].y = lrelu(hs2 + hd2 + et);
        }
    }
    R[threadIdx.x] = etsum;
    __syncthreads();
    for (int off = 128; off > 0; off >>= 1){
        if (threadIdx.x < off) R[threadIdx.x] += R[threadIdx.x + off];
        __syncthreads();
    }
    if (threadIdx.x == 0) atomicAdd(&qw[3], R[0]);
}

__global__ void
k_c2(float* __restrict__ q, float invE)
{
    if (threadIdx.x == 0 && blockIdx.x == 0) q[12] = q[3] * invE;
}

// ---------- layer 2: gather, exact max, fused output ----------
__global__ void __launch_bounds__(256)
k_l2(const unsigned int* __restrict__ rowptr, const unsigned int* __restrict__ ofs,
     const float2* __restrict__ sg, const float* __restrict__ xagg,
     const float* __restrict__ q, const float* __restrict__ b2,
     float* __restrict__ outn, int N)
{
    __shared__ float sq[64];
    if (threadIdx.x < 64) sq[threadIdx.x] = q[threadIdx.x];
    __syncthreads();
    int d = blockIdx.x*256 + threadIdx.x;
    if (d >= N) return;
    float4 xa = ((const float4*)xagg)[d];
    float h2d0 = xa.x*sq[28] + xa.y*sq[30] + xa.z*sq[32] + xa.w*sq[34] + sq[36];
    float h2d1 = xa.x*sq[29] + xa.y*sq[31] + xa.z*sq[33] + xa.w*sq[35] + sq[37];
    float hs2 = xa.x*sq[40] + xa.y*sq[41] + xa.z*sq[42] + xa.w*sq[43] + sq[44];
    float hd2 = xa.x*sq[45] + xa.y*sq[46] + xa.z*sq[47] + xa.w*sq[48] + sq[49];
    float aself = lrelu(hs2 + hd2 + sq[12]);
    unsigned int beg = rowptr[d], end = ofs[d];
    float m = aself;
    for (unsigned int j = beg; j < end; j++)
        m = fmaxf(m, sg[j].y);
    float z = expf(aself - m);
    float acc0 = z*h2d0, acc1 = z*h2d1;
    for (unsigned int j = beg; j < end; j++){
        float2 r = sg[j];
        int s = __float_as_int(r.x);
        float p = expf(r.y - m);
        z += p;
        float4 xs = ((const float4*)xagg)[s];
        float h0 = xs.x*sq[28] + xs.y*sq[30] + xs.z*sq[32] + xs.w*sq[34] + sq[36];
        float h1 = xs.x*sq[29] + xs.y*sq[31] + xs.z*sq[33] + xs.w*sq[35] + sq[37];
        acc0 += p*h0;
        acc1 += p*h1;
    }
    float inv = 1.0f / z;
    float v0 = acc0*inv + b2[0];
    float v1 = acc1*inv + b2[1];
    float mm = fmaxf(v0, v1);
    float ls = logf(expf(v0-mm) + expf(v1-mm)) + mm;
    float2 o;
    o.x = v0 - ls;
    o.y = v1 - ls;
    ((float2*)outn)[d] = o;
}

extern "C" void kernel_launch(void* const* d_in, const int* in_sizes, int n_in,
                              void* d_out, int out_size, void* d_ws, size_t ws_size,
                              hipStream_t stream)
{
    const float* x   = (const float*)d_in[0];
    const int*   ei  = (const int*)  d_in[1];
    const float* ea  = (const float*)d_in[2];
    const float* W1  = (const float*)d_in[3];
    const float* as1 = (const float*)d_in[4];
    const float* ad1 = (const float*)d_in[5];
    const float* We1 = (const float*)d_in[6];
    const float* ae1 = (const float*)d_in[7];
    const float* b1  = (const float*)d_in[8];
    const float* Wm1 = (const float*)d_in[9];
    const float* bm1 = (const float*)d_in[10];
    const float* Wm2 = (const float*)d_in[11];
    const float* bm2 = (const float*)d_in[12];
    const float* Wm3 = (const float*)d_in[13];
    const float* bm3 = (const float*)d_in[14];
    const float* Wm4 = (const float*)d_in[15];
    const float* bm4 = (const float*)d_in[16];
    const float* W2  = (const float*)d_in[17];
    const float* as2 = (const float*)d_in[18];
    const float* ad2 = (const float*)d_in[19];
    const float* We2 = (const float*)d_in[20];
    const float* ae2 = (const float*)d_in[21];
    const float* b2  = (const float*)d_in[22];

    const int N = in_sizes[0] / 4;
    const int E = in_sizes[1] / 2;

    int nb_n = (N + 255) / 256;
    int nb_e = (E + 255) / 256;
    int nb_e4 = (E + 1023) / 1024;
    if (nb_n > 1024) return;

    // ws: q(256) | ofs(N u32) | rowptr(N u32) | aux(1024 u32) | xagg(4N) | sg(2E)
    size_t needFloats = 256 + 2*(size_t)N + 1024 + 4*(size_t)N + 2*(size_t)E;
    if (ws_size < needFloats*sizeof(float)) return;

    float* ws = (float*)d_ws;
    float* q  = ws;
    unsigned int* ofs    = (unsigned int*)(ws + 256);
    unsigned int* rowptr = ofs + N;
    unsigned int* aux    = rowptr + N;
    float* xagg = ws + 256 + 2*(size_t)N + 1024;
    float2* sg  = (float2*)(xagg + 4*(size_t)N);

    hipMemsetAsync(d_ws, 0, (256 + (size_t)N)*sizeof(float), stream);

    float* outn = (float*)d_out;
    float* oute = outn + 2*(size_t)N;

    float invE = 1.0f / (float)E;

    k_sums<<<1024,256,0,stream>>>(ea, q, E);
    k_prep<<<1,64,0,stream>>>(W1, as1, ad1, We1, ae1, b1, Wm1, bm1,
                              W2, as2, ad2, We2, ae2, q, invE);
    k_hist<<<nb_e,256,0,stream>>>(ei, ofs, E);
    k_scan1<<<nb_n,256,0,stream>>>(ofs, rowptr, aux, N);
    k_scan2<<<1,1024,0,stream>>>(aux, nb_n);
    k_scan3<<<nb_n,256,0,stream>>>(rowptr, ofs, aux, N);
    k_scatter<<<nb_e,256,0,stream>>>(ei, ea, q, ofs, sg, oute, E);
    k_l1<<<nb_n,256,0,stream>>>(rowptr, ofs, sg, x, q, xagg, N);
    k_mlp<<<nb_e4,256,0,stream>>>(ei, ea, xagg, Wm1, Wm2, bm2, Wm3, bm3,
                                  Wm4, bm4, q, q, sg, oute, E);
    k_c2<<<1,64,0,stream>>>(q, invE);
    k_l2<<<nb_n,256,0,stream>>>(rowptr, ofs, sg, xagg, q, b2, outn, N);
}

// Round 18
// 809.857 us; speedup vs baseline: 5.6126x; 1.1160x over previous
//
#include <hip/hip_runtime.h>
#include <hip/hip_bf16.h>

static __device__ __forceinline__ float lrelu(float v){ return v >= 0.f ? v : 0.2f*v; }

#define FMA4(D_, S_, V_) { D_.x += (S_)*(V_).x; D_.y += (S_)*(V_).y; \
                           D_.z += (S_)*(V_).z; D_.w += (S_)*(V_).w; }

// q slots (256 floats):
// 0..2 sum(ea cols) | 3 sum(et2) | 4..6 g1 | 7 c1 | 8..11 g2 | 12 c2(unused)
// 16..19 vs1 | 20..23 vd1 | 28..35 PM | 36..37 Q
// 40..43 S | 44 s0 | 45..48 D | 49 d0
// 64..127 A=W1@Wm1_top | 128..191 B=W1@Wm1_bot | 192..207 bb

// merged: ea column sums + dst histogram (one edge pass)
__global__ void __launch_bounds__(256)
k_histsum(const int* __restrict__ ei, const float* __restrict__ ea,
          float* __restrict__ q, unsigned int* __restrict__ ofs, int E)
{
    float s0 = 0.f, s1 = 0.f, s2 = 0.f;
    int stride = gridDim.x * blockDim.x;
    for (int e = blockIdx.x*blockDim.x + threadIdx.x; e < E; e += stride){
        size_t o = 3*(size_t)e;
        s0 += ea[o]; s1 += ea[o+1]; s2 += ea[o+2];
        atomicAdd(&ofs[ei[E + e]], 1u);
    }
    for (int o = 32; o > 0; o >>= 1){
        s0 += __shfl_down(s0, o);
        s1 += __shfl_down(s1, o);
        s2 += __shfl_down(s2, o);
    }
    if ((threadIdx.x & 63) == 0){
        atomicAdd(&q[0], s0); atomicAdd(&q[1], s1); atomicAdd(&q[2], s2);
    }
}

__global__ void
k_prep(const float* __restrict__ W1, const float* __restrict__ as1,
       const float* __restrict__ ad1,
       const float* __restrict__ We1, const float* __restrict__ ae1,
       const float* __restrict__ b1,
       const float* __restrict__ Wm1, const float* __restrict__ bm1,
       const float* __restrict__ W2, const float* __restrict__ as2,
       const float* __restrict__ ad2,
       const float* __restrict__ We2, const float* __restrict__ ae2,
       float* __restrict__ q, float invE)
{
    __shared__ float sPM[8], sQ[2];
    int t = threadIdx.x;
    if (t < 16){
        int j = t;
        float a0=0,a1=0,a2=0,a3=0, c0=0,c1v=0,c2v=0,c3=0, tb=0;
        for (int i = 0; i < 16; i++){
            float wt = Wm1[i*16 + j];
            float wb = Wm1[(19+i)*16 + j];
            a0 += W1[0*16+i]*wt; a1 += W1[1*16+i]*wt;
            a2 += W1[2*16+i]*wt; a3 += W1[3*16+i]*wt;
            c0 += W1[0*16+i]*wb; c1v += W1[1*16+i]*wb;
            c2v += W1[2*16+i]*wb; c3 += W1[3*16+i]*wb;
            tb += b1[i]*(wt + wb);
        }
        q[64+0*16+j] = a0; q[64+1*16+j] = a1; q[64+2*16+j] = a2; q[64+3*16+j] = a3;
        q[128+0*16+j] = c0; q[128+1*16+j] = c1v; q[128+2*16+j] = c2v; q[128+3*16+j] = c3;
        q[192+j] = bm1[j] + tb;
    } else if (t < 20){
        int c = t - 16;
        float vs = 0.f, vd = 0.f, p0 = 0.f, p1 = 0.f;
        for (int i = 0; i < 16; i++){
            float w = W1[c*16 + i];
            vs += w * as1[i];
            vd += w * ad1[i];
            p0 += w * W2[i*2 + 0];
            p1 += w * W2[i*2 + 1];
        }
        q[16+c] = vs; q[20+c] = vd;
        q[28+c*2+0] = p0; q[28+c*2+1] = p1;
        sPM[c*2+0] = p0; sPM[c*2+1] = p1;
    } else if (t == 20){
        float c1 = 0.f;
        for (int k = 0; k < 3; k++){
            float g = 0.f;
            for (int j = 0; j < 16; j++) g += We1[k*16 + j] * ae1[j];
            q[4+k] = g;
            c1 += q[k] * invE * g;
        }
        q[7] = c1;
    } else if (t == 21){
        for (int k = 0; k < 4; k++)
            q[8+k] = We2[k*2] * ae2[0] + We2[k*2+1] * ae2[1];
    } else if (t == 22){
        float q0 = 0.f, q1 = 0.f;
        for (int i = 0; i < 16; i++){
            q0 += b1[i] * W2[i*2];
            q1 += b1[i] * W2[i*2+1];
        }
        q[36] = q0; q[37] = q1;
        sQ[0] = q0; sQ[1] = q1;
    }
    __syncthreads();
    if (t == 0){
        float a0 = as2[0], a1 = as2[1], d0 = ad2[0], d1 = ad2[1];
        for (int c = 0; c < 4; c++){
            q[40+c] = sPM[c*2]*a0 + sPM[c*2+1]*a1;
            q[45+c] = sPM[c*2]*d0 + sPM[c*2+1]*d1;
        }
        q[44] = sQ[0]*a0 + sQ[1]*a1;
        q[49] = sQ[0]*d0 + sQ[1]*d1;
    }
}

__global__ void __launch_bounds__(256)
k_scan1(const unsigned int* __restrict__ cnt, unsigned int* __restrict__ rowptr,
        unsigned int* __restrict__ aux, int N)
{
    __shared__ unsigned int s[256];
    int t = threadIdx.x;
    int i = blockIdx.x*256 + t;
    unsigned int v = (i < N) ? cnt[i] : 0u;
    s[t] = v;
    __syncthreads();
    for (int off = 1; off < 256; off <<= 1){
        unsigned int add = (t >= off) ? s[t-off] : 0u;
        __syncthreads();
        s[t] += add;
        __syncthreads();
    }
    if (i < N) rowptr[i] = s[t] - v;
    if (t == 255) aux[blockIdx.x] = s[t];
}

__global__ void __launch_bounds__(1024)
k_scan2(unsigned int* __restrict__ aux, int nbs)
{
    __shared__ unsigned int s[1024];
    int t = threadIdx.x;
    unsigned int v = (t < nbs) ? aux[t] : 0u;
    s[t] = v;
    __syncthreads();
    for (int off = 1; off < 1024; off <<= 1){
        unsigned int add = (t >= off) ? s[t-off] : 0u;
        __syncthreads();
        s[t] += add;
        __syncthreads();
    }
    if (t < nbs) aux[t] = s[t] - v;
}

__global__ void __launch_bounds__(256)
k_scan3(unsigned int* __restrict__ rowptr, unsigned int* __restrict__ ofs,
        const unsigned int* __restrict__ aux, int N)
{
    int i = blockIdx.x*256 + threadIdx.x;
    if (i >= N) return;
    unsigned int r = rowptr[i] + aux[blockIdx.x];
    rowptr[i] = r;
    ofs[i] = r;
}

__global__ void __launch_bounds__(256)
k_scatter(const int* __restrict__ ei, const float* __restrict__ ea,
          const float* __restrict__ q, unsigned int* __restrict__ ofs,
          float2* __restrict__ sg, int* __restrict__ posArr, int posStride, int E)
{
    int e = blockIdx.x*256 + threadIdx.x;
    if (e >= E) return;
    int s = ei[e], d = ei[E + e];
    size_t o = 3*(size_t)e;
    float ge = ea[o]*q[4] + ea[o+1]*q[5] + ea[o+2]*q[6];
    unsigned int pos = atomicAdd(&ofs[d], 1u);
    float2 r;
    r.x = __int_as_float(s);
    r.y = ge;
    sg[pos] = r;
    posArr[(size_t)e * posStride] = (int)pos;
}

// ---------- layer 1: gather, 2-way unrolled ----------
__global__ void __launch_bounds__(256)
k_l1(const unsigned int* __restrict__ rowptr, const unsigned int* __restrict__ ofs,
     const float2* __restrict__ sg, const float* __restrict__ x,
     const float* __restrict__ q, float* __restrict__ xagg, int N)
{
    __shared__ float sq[32];
    if (threadIdx.x < 32) sq[threadIdx.x] = q[threadIdx.x];
    __syncthreads();
    int d = blockIdx.x*256 + threadIdx.x;
    if (d >= N) return;
    float4 xd = ((const float4*)x)[d];
    float hd = xd.x*sq[20] + xd.y*sq[21] + xd.z*sq[22] + xd.w*sq[23];
    float hs_self = xd.x*sq[16] + xd.y*sq[17] + xd.z*sq[18] + xd.w*sq[19];
    float p = expf(fminf(lrelu(hs_self + hd + sq[7]), 60.0f));
    float z0 = p, z1v = 0.f;
    float4 acc0, acc1;
    acc0.x = p*xd.x; acc0.y = p*xd.y; acc0.z = p*xd.z; acc0.w = p*xd.w;
    acc1.x = 0.f; acc1.y = 0.f; acc1.z = 0.f; acc1.w = 0.f;
    unsigned int beg = rowptr[d], end = ofs[d];
    unsigned int j = beg;
    for (; j + 1 < end; j += 2){
        float2 r0 = sg[j];
        float2 r1 = sg[j+1];
        int s0 = __float_as_int(r0.x);
        int s1 = __float_as_int(r1.x);
        float4 xs0 = ((const float4*)x)[s0];
        float4 xs1 = ((const float4*)x)[s1];
        float av0 = xs0.x*sq[16] + xs0.y*sq[17] + xs0.z*sq[18] + xs0.w*sq[19] + hd + r0.y;
        float av1 = xs1.x*sq[16] + xs1.y*sq[17] + xs1.z*sq[18] + xs1.w*sq[19] + hd + r1.y;
        float pv0 = expf(fminf(lrelu(av0), 60.0f));
        float pv1 = expf(fminf(lrelu(av1), 60.0f));
        z0 += pv0; z1v += pv1;
        FMA4(acc0, pv0, xs0);
        FMA4(acc1, pv1, xs1);
    }
    if (j < end){
        float2 r0 = sg[j];
        int s0 = __float_as_int(r0.x);
        float4 xs0 = ((const float4*)x)[s0];
        float av0 = xs0.x*sq[16] + xs0.y*sq[17] + xs0.z*sq[18] + xs0.w*sq[19] + hd + r0.y;
        float pv0 = expf(fminf(lrelu(av0), 60.0f));
        z0 += pv0;
        FMA4(acc0, pv0, xs0);
    }
    float inv = 1.0f / (z0 + z1v);
    float4 acc;
    acc.x = (acc0.x + acc1.x) * inv;
    acc.y = (acc0.y + acc1.y) * inv;
    acc.z = (acc0.z + acc1.z) * inv;
    acc.w = (acc0.w + acc1.w) * inv;
    ((float4*)xagg)[d] = acc;
}

// ---------- edge MLP: 4 edges per thread ----------
__global__ void __launch_bounds__(256)
k_mlp(const int* __restrict__ ei, const float* __restrict__ ea,
      const float* __restrict__ xagg,
      const float* __restrict__ Wm1, const float* __restrict__ Wm2,
      const float* __restrict__ bm2, const float* __restrict__ Wm3,
      const float* __restrict__ bm3, const float* __restrict__ Wm4,
      const float* __restrict__ bm4,
      const float* __restrict__ q, float* __restrict__ qw,
      float2* __restrict__ sg, const int* __restrict__ posArr, int posStride,
      float* oute, int E)
{
    __shared__ __align__(16) float L[656];
    __shared__ float R[256];
    for (int t = threadIdx.x; t < 656; t += 256){
        float v;
        if      (t < 128)  v = q[64 + t];
        else if (t < 144)  v = q[192 + (t-128)];
        else if (t < 192)  v = Wm1[256 + (t-144)];
        else if (t < 448)  v = Wm2[t-192];
        else if (t < 464)  v = bm2[t-448];
        else if (t < 592)  v = Wm3[t-464];
        else if (t < 600)  v = bm3[t-592];
        else if (t < 632)  v = Wm4[t-600];
        else if (t < 636)  v = bm4[t-632];
        else if (t < 640)  v = q[8 + (t-636)];
        else               v = q[40 + (t-640)];
        L[t] = v;
    }
    __syncthreads();
    const float4* A4  = (const float4*)(L);
    const float4* B4  = (const float4*)(L + 64);
    const float4* bb4 = (const float4*)(L + 128);
    const float4* C34 = (const float4*)(L + 144);
    const float4* W24 = (const float4*)(L + 192);
    const float4* B24 = (const float4*)(L + 448);
    const float4* W34 = (const float4*)(L + 464);
    const float4* B34 = (const float4*)(L + 592);
    const float4* W44 = (const float4*)(L + 600);
    const float*  sg2v = L + 636;
    const float*  SD  = L + 640;

    int tg = blockIdx.x*256 + threadIdx.x;
    int e0 = tg*4;
    float etsum = 0.f;
    if (e0 + 3 < E){
        int4 sis = ((const int4*)ei)[tg];
        int4 dis = ((const int4*)(ei + E))[tg];
        int si[4] = { sis.x, sis.y, sis.z, sis.w };
        int di[4] = { dis.x, dis.y, dis.z, dis.w };
        float4 eA = ((const float4*)ea)[3*tg+0];
        float4 eB = ((const float4*)ea)[3*tg+1];
        float4 eC = ((const float4*)ea)[3*tg+2];
        float eaf[4][3] = {
            { eA.x, eA.y, eA.z },
            { eA.w, eB.x, eB.y },
            { eB.z, eB.w, eC.x },
            { eC.y, eC.z, eC.w }
        };
        int stash[4];
        #pragma unroll
        for (int k = 0; k < 4; k++)
            stash[k] = posArr[(size_t)(e0+k) * posStride];

        float xsf[4][4], xdf[4][4], hsd[4];
        #pragma unroll
        for (int k = 0; k < 4; k++){
            float4 xs = ((const float4*)xagg)[si[k]];
            float4 xd = ((const float4*)xagg)[di[k]];
            xsf[k][0]=xs.x; xsf[k][1]=xs.y; xsf[k][2]=xs.z; xsf[k][3]=xs.w;
            xdf[k][0]=xd.x; xdf[k][1]=xd.y; xdf[k][2]=xd.z; xdf[k][3]=xd.w;
            float hs2 = xs.x*SD[0] + xs.y*SD[1] + xs.z*SD[2] + xs.w*SD[3] + SD[4];
            float hd2 = xd.x*SD[5] + xd.y*SD[6] + xd.z*SD[7] + xd.w*SD[8] + SD[9];
            hsd[k] = hs2 + hd2;
        }

        float u1[4][16];
        #pragma unroll
        for (int j4 = 0; j4 < 4; j4++){
            float4 acc0 = bb4[j4], acc1 = acc0, acc2 = acc0, acc3 = acc0;
            #pragma unroll
            for (int r = 0; r < 4; r++){
                float4 w = A4[r*4 + j4];
                FMA4(acc0, xsf[0][r], w); FMA4(acc1, xsf[1][r], w);
                FMA4(acc2, xsf[2][r], w); FMA4(acc3, xsf[3][r], w);
            }
            #pragma unroll
            for (int r = 0; r < 3; r++){
                float4 w = C34[r*4 + j4];
                FMA4(acc0, eaf[0][r], w); FMA4(acc1, eaf[1][r], w);
                FMA4(acc2, eaf[2][r], w); FMA4(acc3, eaf[3][r], w);
            }
            #pragma unroll
            for (int r = 0; r < 4; r++){
                float4 w = B4[r*4 + j4];
                FMA4(acc0, xdf[0][r], w); FMA4(acc1, xdf[1][r], w);
                FMA4(acc2, xdf[2][r], w); FMA4(acc3, xdf[3][r], w);
            }
            u1[0][j4*4+0]=fmaxf(acc0.x,0.f); u1[0][j4*4+1]=fmaxf(acc0.y,0.f);
            u1[0][j4*4+2]=fmaxf(acc0.z,0.f); u1[0][j4*4+3]=fmaxf(acc0.w,0.f);
            u1[1][j4*4+0]=fmaxf(acc1.x,0.f); u1[1][j4*4+1]=fmaxf(acc1.y,0.f);
            u1[1][j4*4+2]=fmaxf(acc1.z,0.f); u1[1][j4*4+3]=fmaxf(acc1.w,0.f);
            u1[2][j4*4+0]=fmaxf(acc2.x,0.f); u1[2][j4*4+1]=fmaxf(acc2.y,0.f);
            u1[2][j4*4+2]=fmaxf(acc2.z,0.f); u1[2][j4*4+3]=fmaxf(acc2.w,0.f);
            u1[3][j4*4+0]=fmaxf(acc3.x,0.f); u1[3][j4*4+1]=fmaxf(acc3.y,0.f);
            u1[3][j4*4+2]=fmaxf(acc3.z,0.f); u1[3][j4*4+3]=fmaxf(acc3.w,0.f);
        }

        float u2[4][16];
        #pragma unroll
        for (int j4 = 0; j4 < 4; j4++){
            float4 acc0 = B24[j4], acc1 = acc0, acc2 = acc0, acc3 = acc0;
            #pragma unroll
            for (int c = 0; c < 16; c++){
                float4 w = W24[c*4 + j4];
                FMA4(acc0, u1[0][c], w); FMA4(acc1, u1[1][c], w);
                FMA4(acc2, u1[2][c], w); FMA4(acc3, u1[3][c], w);
            }
            u2[0][j4*4+0]=fmaxf(acc0.x,0.f); u2[0][j4*4+1]=fmaxf(acc0.y,0.f);
            u2[0][j4*4+2]=fmaxf(acc0.z,0.f); u2[0][j4*4+3]=fmaxf(acc0.w,0.f);
            u2[1][j4*4+0]=fmaxf(acc1.x,0.f); u2[1][j4*4+1]=fmaxf(acc1.y,0.f);
            u2[1][j4*4+2]=fmaxf(acc1.z,0.f); u2[1][j4*4+3]=fmaxf(acc1.w,0.f);
            u2[2][j4*4+0]=fmaxf(acc2.x,0.f); u2[2][j4*4+1]=fmaxf(acc2.y,0.f);
            u2[2][j4*4+2]=fmaxf(acc2.z,0.f); u2[2][j4*4+3]=fmaxf(acc2.w,0.f);
            u2[3][j4*4+0]=fmaxf(acc3.x,0.f); u2[3][j4*4+1]=fmaxf(acc3.y,0.f);
            u2[3][j4*4+2]=fmaxf(acc3.z,0.f); u2[3][j4*4+3]=fmaxf(acc3.w,0.f);
        }

        float u3[4][8];
        #pragma unroll
        for (int j2 = 0; j2 < 2; j2++){
            float4 acc0 = B34[j2], acc1 = acc0, acc2 = acc0, acc3 = acc0;
            #pragma unroll
            for (int c = 0; c < 16; c++){
                float4 w = W34[c*2 + j2];
                FMA4(acc0, u2[0][c], w); FMA4(acc1, u2[1][c], w);
                FMA4(acc2, u2[2][c], w); FMA4(acc3, u2[3][c], w);
            }
            u3[0][j2*4+0]=fmaxf(acc0.x,0.f); u3[0][j2*4+1]=fmaxf(acc0.y,0.f);
            u3[0][j2*4+2]=fmaxf(acc0.z,0.f); u3[0][j2*4+3]=fmaxf(acc0.w,0.f);
            u3[1][j2*4+0]=fmaxf(acc1.x,0.f); u3[1][j2*4+1]=fmaxf(acc1.y,0.f);
            u3[1][j2*4+2]=fmaxf(acc1.z,0.f); u3[1][j2*4+3]=fmaxf(acc1.w,0.f);
            u3[2][j2*4+0]=fmaxf(acc2.x,0.f); u3[2][j2*4+1]=fmaxf(acc2.y,0.f);
            u3[2][j2*4+2]=fmaxf(acc2.z,0.f); u3[2][j2*4+3]=fmaxf(acc2.w,0.f);
            u3[3][j2*4+0]=fmaxf(acc3.x,0.f); u3[3][j2*4+1]=fmaxf(acc3.y,0.f);
            u3[3][j2*4+2]=fmaxf(acc3.z,0.f); u3[3][j2*4+3]=fmaxf(acc3.w,0.f);
        }

        float4 ev[4];
        {
            float4 b4v = *(const float4*)(L + 632);
            ev[0] = b4v; ev[1] = b4v; ev[2] = b4v; ev[3] = b4v;
            #pragma unroll
            for (int c = 0; c < 8; c++){
                float4 w = W44[c];
                FMA4(ev[0], u3[0][c], w); FMA4(ev[1], u3[1][c], w);
                FMA4(ev[2], u3[2][c], w); FMA4(ev[3], u3[3][c], w);
            }
        }

        #pragma unroll
        for (int k = 0; k < 4; k++){
            float4 e4 = ev[k];
            float mx = fmaxf(fmaxf(e4.x, e4.y), fmaxf(e4.z, e4.w));
            float ls = logf(expf(e4.x-mx)+expf(e4.y-mx)+expf(e4.z-mx)+expf(e4.w-mx)) + mx;
            float4 o;
            o.x = e4.x-ls; o.y = e4.y-ls; o.z = e4.z-ls; o.w = e4.w-ls;
            ((float4*)oute)[e0+k] = o;
            float et = e4.x*sg2v[0] + e4.y*sg2v[1] + e4.z*sg2v[2] + e4.w*sg2v[3];
            etsum += et;
            sg[stash[k]].y = lrelu(hsd[k] + et);
        }
    } else if (e0 < E){
        for (int e = e0; e < E; e++){
            int sp = posArr[(size_t)e * posStride];
            int si = ei[e], di = ei[E+e];
            float4 xs = ((const float4*)xagg)[si];
            float4 xd = ((const float4*)xagg)[di];
            size_t eo = 3*(size_t)e;
            float e0v = ea[eo], e1v = ea[eo+1], e2v = ea[eo+2];
            float u1s[16];
            #pragma unroll
            for (int j4 = 0; j4 < 4; j4++){
                float4 acc = bb4[j4];
                FMA4(acc, xs.x, A4[0*4+j4]); FMA4(acc, xs.y, A4[1*4+j4]);
                FMA4(acc, xs.z, A4[2*4+j4]); FMA4(acc, xs.w, A4[3*4+j4]);
                FMA4(acc, e0v, C34[0*4+j4]); FMA4(acc, e1v, C34[1*4+j4]);
                FMA4(acc, e2v, C34[2*4+j4]);
                FMA4(acc, xd.x, B4[0*4+j4]); FMA4(acc, xd.y, B4[1*4+j4]);
                FMA4(acc, xd.z, B4[2*4+j4]); FMA4(acc, xd.w, B4[3*4+j4]);
                u1s[j4*4+0]=fmaxf(acc.x,0.f); u1s[j4*4+1]=fmaxf(acc.y,0.f);
                u1s[j4*4+2]=fmaxf(acc.z,0.f); u1s[j4*4+3]=fmaxf(acc.w,0.f);
            }
            float u2s[16];
            #pragma unroll
            for (int j4 = 0; j4 < 4; j4++){
                float4 acc = B24[j4];
                #pragma unroll
                for (int c = 0; c < 16; c++) FMA4(acc, u1s[c], W24[c*4+j4]);
                u2s[j4*4+0]=fmaxf(acc.x,0.f); u2s[j4*4+1]=fmaxf(acc.y,0.f);
                u2s[j4*4+2]=fmaxf(acc.z,0.f); u2s[j4*4+3]=fmaxf(acc.w,0.f);
            }
            float u3s[8];
            #pragma unroll
            for (int j2 = 0; j2 < 2; j2++){
                float4 acc = B34[j2];
                #pragma unroll
                for (int c = 0; c < 16; c++) FMA4(acc, u2s[c], W34[c*2+j2]);
                u3s[j2*4+0]=fmaxf(acc.x,0.f); u3s[j2*4+1]=fmaxf(acc.y,0.f);
                u3s[j2*4+2]=fmaxf(acc.z,0.f); u3s[j2*4+3]=fmaxf(acc.w,0.f);
            }
            float4 e4 = *(const float4*)(L + 632);
            #pragma unroll
            for (int c = 0; c < 8; c++) FMA4(e4, u3s[c], W44[c]);
            float mx = fmaxf(fmaxf(e4.x, e4.y), fmaxf(e4.z, e4.w));
            float ls = logf(expf(e4.x-mx)+expf(e4.y-mx)+expf(e4.z-mx)+expf(e4.w-mx)) + mx;
            float4 o;
            o.x = e4.x-ls; o.y = e4.y-ls; o.z = e4.z-ls; o.w = e4.w-ls;
            ((float4*)oute)[e] = o;
            float et = e4.x*sg2v[0] + e4.y*sg2v[1] + e4.z*sg2v[2] + e4.w*sg2v[3];
            etsum += et;
            float hs2 = xs.x*SD[0] + xs.y*SD[1] + xs.z*SD[2] + xs.w*SD[3] + SD[4];
            float hd2 = xd.x*SD[5] + xd.y*SD[6] + xd.z*SD[7] + xd.w*SD[8] + SD[9];
            sg[sp].y = lrelu(hs2 + hd2 + et);
        }
    }
    R[threadIdx.x] = etsum;
    __syncthreads();
    for (int off = 128; off > 0; off >>= 1){
        if (threadIdx.x < off) R[threadIdx.x] += R[threadIdx.x + off];
        __syncthreads();
    }
    if (threadIdx.x == 0) atomicAdd(&qw[3], R[0]);
}

// ---------- layer 2: single-pass online softmax, fused output ----------
__global__ void __launch_bounds__(256)
k_l2(const unsigned int* __restrict__ rowptr, const unsigned int* __restrict__ ofs,
     const float2* __restrict__ sg, const float* __restrict__ xagg,
     const float* __restrict__ q, const float* __restrict__ b2,
     float* __restrict__ outn, float invE, int N)
{
    __shared__ float sq[64];
    if (threadIdx.x < 64) sq[threadIdx.x] = q[threadIdx.x];
    __syncthreads();
    int d = blockIdx.x*256 + threadIdx.x;
    if (d >= N) return;
    float c2 = sq[3] * invE;
    float4 xa = ((const float4*)xagg)[d];
    float h2d0 = xa.x*sq[28] + xa.y*sq[30] + xa.z*sq[32] + xa.w*sq[34] + sq[36];
    float h2d1 = xa.x*sq[29] + xa.y*sq[31] + xa.z*sq[33] + xa.w*sq[35] + sq[37];
    float hs2 = xa.x*sq[40] + xa.y*sq[41] + xa.z*sq[42] + xa.w*sq[43] + sq[44];
    float hd2 = xa.x*sq[45] + xa.y*sq[46] + xa.z*sq[47] + xa.w*sq[48] + sq[49];
    float aself = lrelu(hs2 + hd2 + c2);

    // state A seeded with self-loop; state B empty
    float mA = aself, zA = 1.f, a0A = h2d0, a1A = h2d1;
    float mB = -1e30f, zB = 0.f, a0B = 0.f, a1B = 0.f;

    unsigned int beg = rowptr[d], end = ofs[d];
    unsigned int j = beg;
    for (; j + 1 < end; j += 2){
        float2 r0 = sg[j];
        float2 r1 = sg[j+1];
        int s0 = __float_as_int(r0.x);
        int s1 = __float_as_int(r1.x);
        float4 xs0 = ((const float4*)xagg)[s0];
        float4 xs1 = ((const float4*)xagg)[s1];
        float h00 = xs0.x*sq[28] + xs0.y*sq[30] + xs0.z*sq[32] + xs0.w*sq[34] + sq[36];
        float h01 = xs0.x*sq[29] + xs0.y*sq[31] + xs0.z*sq[33] + xs0.w*sq[35] + sq[37];
        float h10 = xs1.x*sq[28] + xs1.y*sq[30] + xs1.z*sq[32] + xs1.w*sq[34] + sq[36];
        float h11 = xs1.x*sq[29] + xs1.y*sq[31] + xs1.z*sq[33] + xs1.w*sq[35] + sq[37];
        float mn0 = fmaxf(mA, r0.y);
        float sc0 = expf(mA - mn0);
        float p0  = expf(r0.y - mn0);
        zA  = zA*sc0 + p0;
        a0A = a0A*sc0 + p0*h00;
        a1A = a1A*sc0 + p0*h01;
        mA = mn0;
        float mn1 = fmaxf(mB, r1.y);
        float sc1 = expf(mB - mn1);
        float p1  = expf(r1.y - mn1);
        zB  = zB*sc1 + p1;
        a0B = a0B*sc1 + p1*h10;
        a1B = a1B*sc1 + p1*h11;
        mB = mn1;
    }
    if (j < end){
        float2 r0 = sg[j];
        int s0 = __float_as_int(r0.x);
        float4 xs0 = ((const float4*)xagg)[s0];
        float h00 = xs0.x*sq[28] + xs0.y*sq[30] + xs0.z*sq[32] + xs0.w*sq[34] + sq[36];
        float h01 = xs0.x*sq[29] + xs0.y*sq[31] + xs0.z*sq[33] + xs0.w*sq[35] + sq[37];
        float mn0 = fmaxf(mA, r0.y);
        float sc0 = expf(mA - mn0);
        float p0  = expf(r0.y - mn0);
        zA  = zA*sc0 + p0;
        a0A = a0A*sc0 + p0*h00;
        a1A = a1A*sc0 + p0*h01;
        mA = mn0;
    }
    float m = fmaxf(mA, mB);
    float sA = expf(mA - m), sB = expf(mB - m);
    float z = zA*sA + zB*sB;
    float inv = 1.0f / z;
    float v0 = (a0A*sA + a0B*sB)*inv + b2[0];
    float v1 = (a1A*sA + a1B*sB)*inv + b2[1];
    float mm = fmaxf(v0, v1);
    float ls = logf(expf(v0-mm) + expf(v1-mm)) + mm;
    float2 o;
    o.x = v0 - ls;
    o.y = v1 - ls;
    ((float2*)outn)[d] = o;
}

extern "C" void kernel_launch(void* const* d_in, const int* in_sizes, int n_in,
                              void* d_out, int out_size, void* d_ws, size_t ws_size,
                              hipStream_t stream)
{
    const float* x   = (const float*)d_in[0];
    const int*   ei  = (const int*)  d_in[1];
    const float* ea  = (const float*)d_in[2];
    const float* W1  = (const float*)d_in[3];
    const float* as1 = (const float*)d_in[4];
    const float* ad1 = (const float*)d_in[5];
    const float* We1 = (const float*)d_in[6];
    const float* ae1 = (const float*)d_in[7];
    const float* b1  = (const float*)d_in[8];
    const float* Wm1 = (const float*)d_in[9];
    const float* bm1 = (const float*)d_in[10];
    const float* Wm2 = (const float*)d_in[11];
    const float* bm2 = (const float*)d_in[12];
    const float* Wm3 = (const float*)d_in[13];
    const float* bm3 = (const float*)d_in[14];
    const float* Wm4 = (const float*)d_in[15];
    const float* bm4 = (const float*)d_in[16];
    const float* W2  = (const float*)d_in[17];
    const float* as2 = (const float*)d_in[18];
    const float* ad2 = (const float*)d_in[19];
    const float* We2 = (const float*)d_in[20];
    const float* ae2 = (const float*)d_in[21];
    const float* b2  = (const float*)d_in[22];

    const int N = in_sizes[0] / 4;
    const int E = in_sizes[1] / 2;

    int nb_n = (N + 255) / 256;
    int nb_e = (E + 255) / 256;
    int nb_e4 = (E + 1023) / 1024;
    if (nb_n > 1024) return;

    // base ws: q(256) | ofs(N u32) | rowptr(N u32) | aux(1024 u32) | xagg(4N) | sg(2E)
    size_t baseFloats = 256 + 2*(size_t)N + 1024 + 4*(size_t)N + 2*(size_t)E;
    if (ws_size < baseFloats*sizeof(float)) return;

    float* ws = (float*)d_ws;
    float* q  = ws;
    unsigned int* ofs    = (unsigned int*)(ws + 256);
    unsigned int* rowptr = ofs + N;
    unsigned int* aux    = rowptr + N;
    float* xagg = ws + 256 + 2*(size_t)N + 1024;
    float2* sg  = (float2*)(xagg + 4*(size_t)N);

    float* outn = (float*)d_out;
    float* oute = outn + 2*(size_t)N;

    // optional contiguous pos buffer (coalesced stash) if workspace allows
    size_t bigFloats = baseFloats + (size_t)E;
    int* posArr;
    int posStride;
    if (ws_size >= bigFloats*sizeof(float)){
        posArr = (int*)(sg + (size_t)E);   // E ints after sg (sg occupies 2E floats = E float2)
        posStride = 1;
    } else {
        posArr = (int*)oute;               // stash at oute[4e] (proven fallback)
        posStride = 4;
    }

    hipMemsetAsync(d_ws, 0, (256 + (size_t)N)*sizeof(float), stream);

    float invE = 1.0f / (float)E;

    k_histsum<<<1024,256,0,stream>>>(ei, ea, q, ofs, E);
    k_prep<<<1,64,0,stream>>>(W1, as1, ad1, We1, ae1, b1, Wm1, bm1,
                              W2, as2, ad2, We2, ae2, q, invE);
    k_scan1<<<nb_n,256,0,stream>>>(ofs, rowptr, aux, N);
    k_scan2<<<1,1024,0,stream>>>(aux, nb_n);
    k_scan3<<<nb_n,256,0,stream>>>(rowptr, ofs, aux, N);
    k_scatter<<<nb_e,256,0,stream>>>(ei, ea, q, ofs, sg, posArr, posStride, E);
    k_l1<<<nb_n,256,0,stream>>>(rowptr, ofs, sg, x, q, xagg, N);
    k_mlp<<<nb_e4,256,0,stream>>>(ei, ea, xagg, Wm1, Wm2, bm2, Wm3, bm3,
                                  Wm4, bm4, q, q, sg, posArr, posStride, oute, E);
    k_l2<<<nb_n,256,0,stream>>>(rowptr, ofs, sg, xagg, q, b2, outn, invE, N);
}

// Round 19
// 677.349 us; speedup vs baseline: 6.7106x; 1.1956x over previous
//
#include <hip/hip_runtime.h>
#include <hip/hip_bf16.h>

static __device__ __forceinline__ float lrelu(float v){ return v >= 0.f ? v : 0.2f*v; }

#define FMA4(D_, S_, V_) { D_.x += (S_)*(V_).x; D_.y += (S_)*(V_).y; \
                           D_.z += (S_)*(V_).z; D_.w += (S_)*(V_).w; }

// q slots (256 floats):
// 0..2 sum(ea cols) | 3 sum(et2) | 4..6 g1 | 7 c1 | 8..11 g2
// 16..19 vs1 | 20..23 vd1 | 28..35 PM | 36..37 Q
// 40..43 S | 44 s0 | 45..48 D | 49 d0
// 64..127 A=W1@Wm1_top | 128..191 B=W1@Wm1_bot | 192..207 bb

// merged: ea column sums + dst histogram (+ optional rank record)
__global__ void __launch_bounds__(256)
k_hist(const int* __restrict__ ei, const float* __restrict__ ea,
       float* __restrict__ q, unsigned int* __restrict__ cnt,
       unsigned short* __restrict__ rank, int E)
{
    float s0 = 0.f, s1 = 0.f, s2 = 0.f;
    int stride = gridDim.x * blockDim.x;
    for (int e = blockIdx.x*blockDim.x + threadIdx.x; e < E; e += stride){
        size_t o = 3*(size_t)e;
        s0 += ea[o]; s1 += ea[o+1]; s2 += ea[o+2];
        unsigned int r = atomicAdd(&cnt[ei[E + e]], 1u);
        if (rank) rank[e] = (unsigned short)r;
    }
    for (int o = 32; o > 0; o >>= 1){
        s0 += __shfl_down(s0, o);
        s1 += __shfl_down(s1, o);
        s2 += __shfl_down(s2, o);
    }
    if ((threadIdx.x & 63) == 0){
        atomicAdd(&q[0], s0); atomicAdd(&q[1], s1); atomicAdd(&q[2], s2);
    }
}

__global__ void
k_prep(const float* __restrict__ W1, const float* __restrict__ as1,
       const float* __restrict__ ad1,
       const float* __restrict__ We1, const float* __restrict__ ae1,
       const float* __restrict__ b1,
       const float* __restrict__ Wm1, const float* __restrict__ bm1,
       const float* __restrict__ W2, const float* __restrict__ as2,
       const float* __restrict__ ad2,
       const float* __restrict__ We2, const float* __restrict__ ae2,
       float* __restrict__ q, float invE)
{
    __shared__ float sPM[8], sQ[2];
    int t = threadIdx.x;
    if (t < 16){
        int j = t;
        float a0=0,a1=0,a2=0,a3=0, c0=0,c1v=0,c2v=0,c3=0, tb=0;
        for (int i = 0; i < 16; i++){
            float wt = Wm1[i*16 + j];
            float wb = Wm1[(19+i)*16 + j];
            a0 += W1[0*16+i]*wt; a1 += W1[1*16+i]*wt;
            a2 += W1[2*16+i]*wt; a3 += W1[3*16+i]*wt;
            c0 += W1[0*16+i]*wb; c1v += W1[1*16+i]*wb;
            c2v += W1[2*16+i]*wb; c3 += W1[3*16+i]*wb;
            tb += b1[i]*(wt + wb);
        }
        q[64+0*16+j] = a0; q[64+1*16+j] = a1; q[64+2*16+j] = a2; q[64+3*16+j] = a3;
        q[128+0*16+j] = c0; q[128+1*16+j] = c1v; q[128+2*16+j] = c2v; q[128+3*16+j] = c3;
        q[192+j] = bm1[j] + tb;
    } else if (t < 20){
        int c = t - 16;
        float vs = 0.f, vd = 0.f, p0 = 0.f, p1 = 0.f;
        for (int i = 0; i < 16; i++){
            float w = W1[c*16 + i];
            vs += w * as1[i];
            vd += w * ad1[i];
            p0 += w * W2[i*2 + 0];
            p1 += w * W2[i*2 + 1];
        }
        q[16+c] = vs; q[20+c] = vd;
        q[28+c*2+0] = p0; q[28+c*2+1] = p1;
        sPM[c*2+0] = p0; sPM[c*2+1] = p1;
    } else if (t == 20){
        float c1 = 0.f;
        for (int k = 0; k < 3; k++){
            float g = 0.f;
            for (int j = 0; j < 16; j++) g += We1[k*16 + j] * ae1[j];
            q[4+k] = g;
            c1 += q[k] * invE * g;
        }
        q[7] = c1;
    } else if (t == 21){
        for (int k = 0; k < 4; k++)
            q[8+k] = We2[k*2] * ae2[0] + We2[k*2+1] * ae2[1];
    } else if (t == 22){
        float q0 = 0.f, q1 = 0.f;
        for (int i = 0; i < 16; i++){
            q0 += b1[i] * W2[i*2];
            q1 += b1[i] * W2[i*2+1];
        }
        q[36] = q0; q[37] = q1;
        sQ[0] = q0; sQ[1] = q1;
    }
    __syncthreads();
    if (t == 0){
        float a0 = as2[0], a1 = as2[1], d0 = ad2[0], d1 = ad2[1];
        for (int c = 0; c < 4; c++){
            q[40+c] = sPM[c*2]*a0 + sPM[c*2+1]*a1;
            q[45+c] = sPM[c*2]*d0 + sPM[c*2+1]*d1;
        }
        q[44] = sQ[0]*a0 + sQ[1]*a1;
        q[49] = sQ[0]*d0 + sQ[1]*d1;
    }
}

__global__ void __launch_bounds__(256)
k_scan1(const unsigned int* __restrict__ cnt, unsigned int* __restrict__ rowptr,
        unsigned int* __restrict__ aux, int N)
{
    __shared__ unsigned int s[256];
    int t = threadIdx.x;
    int i = blockIdx.x*256 + t;
    unsigned int v = (i < N) ? cnt[i] : 0u;
    s[t] = v;
    __syncthreads();
    for (int off = 1; off < 256; off <<= 1){
        unsigned int add = (t >= off) ? s[t-off] : 0u;
        __syncthreads();
        s[t] += add;
        __syncthreads();
    }
    if (i < N) rowptr[i] = s[t] - v;
    if (t == 255) aux[blockIdx.x] = s[t];
}

__global__ void __launch_bounds__(1024)
k_scan2(unsigned int* __restrict__ aux, int nbs)
{
    __shared__ unsigned int s[1024];
    int t = threadIdx.x;
    unsigned int v = (t < nbs) ? aux[t] : 0u;
    s[t] = v;
    __syncthreads();
    for (int off = 1; off < 1024; off <<= 1){
        unsigned int add = (t >= off) ? s[t-off] : 0u;
        __syncthreads();
        s[t] += add;
        __syncthreads();
    }
    if (t < nbs) aux[t] = s[t] - v;
}

__global__ void __launch_bounds__(256)
k_scan3(unsigned int* __restrict__ rowptr, unsigned int* __restrict__ ofs,
        const unsigned int* __restrict__ aux, int N, int E)
{
    int i = blockIdx.x*256 + threadIdx.x;
    if (i == 0) rowptr[N] = (unsigned int)E;
    if (i >= N) return;
    unsigned int r = rowptr[i] + aux[blockIdx.x];
    rowptr[i] = r;
    ofs[i] = r;   // insert pointers (used only by fallback atomic scatter)
}

__global__ void __launch_bounds__(256)
k_scatter(const int* __restrict__ ei, const float* __restrict__ ea,
          const float* __restrict__ q,
          const unsigned int* __restrict__ rowptr,
          const unsigned short* __restrict__ rank,
          unsigned int* __restrict__ ofs,
          float2* __restrict__ sg, int* __restrict__ posStash, int E)
{
    int e = blockIdx.x*256 + threadIdx.x;
    if (e >= E) return;
    int s = ei[e], d = ei[E + e];
    size_t o = 3*(size_t)e;
    float ge = ea[o]*q[4] + ea[o+1]*q[5] + ea[o+2]*q[6];
    unsigned int pos;
    if (rank){
        pos = rowptr[d] + (unsigned int)rank[e];
    } else {
        pos = atomicAdd(&ofs[d], 1u);
        posStash[4*(size_t)e] = (int)pos;
    }
    float2 r;
    r.x = __int_as_float(s);
    r.y = ge;
    sg[pos] = r;
}

// ---------- layer 1: gather, 2-way unrolled; optional h2 table ----------
__global__ void __launch_bounds__(256)
k_l1(const unsigned int* __restrict__ rowptr,
     const float2* __restrict__ sg, const float* __restrict__ x,
     const float* __restrict__ q, float* __restrict__ xagg,
     float2* __restrict__ h2t, int N)
{
    __shared__ float sq[64];
    if (threadIdx.x < 64) sq[threadIdx.x] = q[threadIdx.x];
    __syncthreads();
    int d = blockIdx.x*256 + threadIdx.x;
    if (d >= N) return;
    float4 xd = ((const float4*)x)[d];
    float hd = xd.x*sq[20] + xd.y*sq[21] + xd.z*sq[22] + xd.w*sq[23];
    float hs_self = xd.x*sq[16] + xd.y*sq[17] + xd.z*sq[18] + xd.w*sq[19];
    float p = expf(fminf(lrelu(hs_self + hd + sq[7]), 60.0f));
    float z0 = p, z1v = 0.f;
    float4 acc0, acc1;
    acc0.x = p*xd.x; acc0.y = p*xd.y; acc0.z = p*xd.z; acc0.w = p*xd.w;
    acc1.x = 0.f; acc1.y = 0.f; acc1.z = 0.f; acc1.w = 0.f;
    unsigned int beg = rowptr[d], end = rowptr[d+1];
    unsigned int j = beg;
    for (; j + 1 < end; j += 2){
        float2 r0 = sg[j];
        float2 r1 = sg[j+1];
        int s0 = __float_as_int(r0.x);
        int s1 = __float_as_int(r1.x);
        float4 xs0 = ((const float4*)x)[s0];
        float4 xs1 = ((const float4*)x)[s1];
        float av0 = xs0.x*sq[16] + xs0.y*sq[17] + xs0.z*sq[18] + xs0.w*sq[19] + hd + r0.y;
        float av1 = xs1.x*sq[16] + xs1.y*sq[17] + xs1.z*sq[18] + xs1.w*sq[19] + hd + r1.y;
        float pv0 = expf(fminf(lrelu(av0), 60.0f));
        float pv1 = expf(fminf(lrelu(av1), 60.0f));
        z0 += pv0; z1v += pv1;
        FMA4(acc0, pv0, xs0);
        FMA4(acc1, pv1, xs1);
    }
    if (j < end){
        float2 r0 = sg[j];
        int s0 = __float_as_int(r0.x);
        float4 xs0 = ((const float4*)x)[s0];
        float av0 = xs0.x*sq[16] + xs0.y*sq[17] + xs0.z*sq[18] + xs0.w*sq[19] + hd + r0.y;
        float pv0 = expf(fminf(lrelu(av0), 60.0f));
        z0 += pv0;
        FMA4(acc0, pv0, xs0);
    }
    float inv = 1.0f / (z0 + z1v);
    float4 acc;
    acc.x = (acc0.x + acc1.x) * inv;
    acc.y = (acc0.y + acc1.y) * inv;
    acc.z = (acc0.z + acc1.z) * inv;
    acc.w = (acc0.w + acc1.w) * inv;
    ((float4*)xagg)[d] = acc;
    if (h2t){
        float2 hh;
        hh.x = acc.x*sq[28] + acc.y*sq[30] + acc.z*sq[32] + acc.w*sq[34] + sq[36];
        hh.y = acc.x*sq[29] + acc.y*sq[31] + acc.z*sq[33] + acc.w*sq[35] + sq[37];
        h2t[d] = hh;
    }
}

// ---------- edge MLP: 4 edges per thread ----------
__global__ void __launch_bounds__(256)
k_mlp(const int* __restrict__ ei, const float* __restrict__ ea,
      const float* __restrict__ xagg,
      const float* __restrict__ Wm1, const float* __restrict__ Wm2,
      const float* __restrict__ bm2, const float* __restrict__ Wm3,
      const float* __restrict__ bm3, const float* __restrict__ Wm4,
      const float* __restrict__ bm4,
      const float* __restrict__ q, float* __restrict__ qw,
      float2* __restrict__ sg,
      const unsigned int* __restrict__ rowptr,
      const unsigned short* __restrict__ rank,
      const int* __restrict__ posStash,
      float* oute, int E)
{
    __shared__ __align__(16) float L[656];
    __shared__ float R[256];
    for (int t = threadIdx.x; t < 656; t += 256){
        float v;
        if      (t < 128)  v = q[64 + t];
        else if (t < 144)  v = q[192 + (t-128)];
        else if (t < 192)  v = Wm1[256 + (t-144)];
        else if (t < 448)  v = Wm2[t-192];
        else if (t < 464)  v = bm2[t-448];
        else if (t < 592)  v = Wm3[t-464];
        else if (t < 600)  v = bm3[t-592];
        else if (t < 632)  v = Wm4[t-600];
        else if (t < 636)  v = bm4[t-632];
        else if (t < 640)  v = q[8 + (t-636)];
        else               v = q[40 + (t-640)];
        L[t] = v;
    }
    __syncthreads();
    const float4* A4  = (const float4*)(L);
    const float4* B4  = (const float4*)(L + 64);
    const float4* bb4 = (const float4*)(L + 128);
    const float4* C34 = (const float4*)(L + 144);
    const float4* W24 = (const float4*)(L + 192);
    const float4* B24 = (const float4*)(L + 448);
    const float4* W34 = (const float4*)(L + 464);
    const float4* B34 = (const float4*)(L + 592);
    const float4* W44 = (const float4*)(L + 600);
    const float*  sg2v = L + 636;
    const float*  SD  = L + 640;

    int tg = blockIdx.x*256 + threadIdx.x;
    int e0 = tg*4;
    float etsum = 0.f;
    if (e0 + 3 < E){
        int4 sis = ((const int4*)ei)[tg];
        int4 dis = ((const int4*)(ei + E))[tg];
        int si[4] = { sis.x, sis.y, sis.z, sis.w };
        int di[4] = { dis.x, dis.y, dis.z, dis.w };
        float4 eA = ((const float4*)ea)[3*tg+0];
        float4 eB = ((const float4*)ea)[3*tg+1];
        float4 eC = ((const float4*)ea)[3*tg+2];
        float eaf[4][3] = {
            { eA.x, eA.y, eA.z },
            { eA.w, eB.x, eB.y },
            { eB.z, eB.w, eC.x },
            { eC.y, eC.z, eC.w }
        };
        int stash[4];
        if (rank){
            ushort4 rr = ((const ushort4*)rank)[tg];
            stash[0] = (int)(rowptr[di[0]] + rr.x);
            stash[1] = (int)(rowptr[di[1]] + rr.y);
            stash[2] = (int)(rowptr[di[2]] + rr.z);
            stash[3] = (int)(rowptr[di[3]] + rr.w);
        } else {
            #pragma unroll
            for (int k = 0; k < 4; k++)
                stash[k] = posStash[4*(size_t)(e0+k)];
        }

        float xsf[4][4], xdf[4][4], hsd[4];
        #pragma unroll
        for (int k = 0; k < 4; k++){
            float4 xs = ((const float4*)xagg)[si[k]];
            float4 xd = ((const float4*)xagg)[di[k]];
            xsf[k][0]=xs.x; xsf[k][1]=xs.y; xsf[k][2]=xs.z; xsf[k][3]=xs.w;
            xdf[k][0]=xd.x; xdf[k][1]=xd.y; xdf[k][2]=xd.z; xdf[k][3]=xd.w;
            float hs2 = xs.x*SD[0] + xs.y*SD[1] + xs.z*SD[2] + xs.w*SD[3] + SD[4];
            float hd2 = xd.x*SD[5] + xd.y*SD[6] + xd.z*SD[7] + xd.w*SD[8] + SD[9];
            hsd[k] = hs2 + hd2;
        }

        float u1[4][16];
        #pragma unroll
        for (int j4 = 0; j4 < 4; j4++){
            float4 acc0 = bb4[j4], acc1 = acc0, acc2 = acc0, acc3 = acc0;
            #pragma unroll
            for (int r = 0; r < 4; r++){
                float4 w = A4[r*4 + j4];
                FMA4(acc0, xsf[0][r], w); FMA4(acc1, xsf[1][r], w);
                FMA4(acc2, xsf[2][r], w); FMA4(acc3, xsf[3][r], w);
            }
            #pragma unroll
            for (int r = 0; r < 3; r++){
                float4 w = C34[r*4 + j4];
                FMA4(acc0, eaf[0][r], w); FMA4(acc1, eaf[1][r], w);
                FMA4(acc2, eaf[2][r], w); FMA4(acc3, eaf[3][r], w);
            }
            #pragma unroll
            for (int r = 0; r < 4; r++){
                float4 w = B4[r*4 + j4];
                FMA4(acc0, xdf[0][r], w); FMA4(acc1, xdf[1][r], w);
                FMA4(acc2, xdf[2][r], w); FMA4(acc3, xdf[3][r], w);
            }
            u1[0][j4*4+0]=fmaxf(acc0.x,0.f); u1[0][j4*4+1]=fmaxf(acc0.y,0.f);
            u1[0][j4*4+2]=fmaxf(acc0.z,0.f); u1[0][j4*4+3]=fmaxf(acc0.w,0.f);
            u1[1][j4*4+0]=fmaxf(acc1.x,0.f); u1[1][j4*4+1]=fmaxf(acc1.y,0.f);
            u1[1][j4*4+2]=fmaxf(acc1.z,0.f); u1[1][j4*4+3]=fmaxf(acc1.w,0.f);
            u1[2][j4*4+0]=fmaxf(acc2.x,0.f); u1[2][j4*4+1]=fmaxf(acc2.y,0.f);
            u1[2][j4*4+2]=fmaxf(acc2.z,0.f); u1[2][j4*4+3]=fmaxf(acc2.w,0.f);
            u1[3][j4*4+0]=fmaxf(acc3.x,0.f); u1[3][j4*4+1]=fmaxf(acc3.y,0.f);
            u1[3][j4*4+2]=fmaxf(acc3.z,0.f); u1[3][j4*4+3]=fmaxf(acc3.w,0.f);
        }

        float u2[4][16];
        #pragma unroll
        for (int j4 = 0; j4 < 4; j4++){
            float4 acc0 = B24[j4], acc1 = acc0, acc2 = acc0, acc3 = acc0;
            #pragma unroll
            for (int c = 0; c < 16; c++){
                float4 w = W24[c*4 + j4];
                FMA4(acc0, u1[0][c], w); FMA4(acc1, u1[1][c], w);
                FMA4(acc2, u1[2][c], w); FMA4(acc3, u1[3][c], w);
            }
            u2[0][j4*4+0]=fmaxf(acc0.x,0.f); u2[0][j4*4+1]=fmaxf(acc0.y,0.f);
            u2[0][j4*4+2]=fmaxf(acc0.z,0.f); u2[0][j4*4+3]=fmaxf(acc0.w,0.f);
            u2[1][j4*4+0]=fmaxf(acc1.x,0.f); u2[1][j4*4+1]=fmaxf(acc1.y,0.f);
            u2[1][j4*4+2]=fmaxf(acc1.z,0.f); u2[1][j4*4+3]=fmaxf(acc1.w,0.f);
            u2[2][j4*4+0]=fmaxf(acc2.x,0.f); u2[2][j4*4+1]=fmaxf(acc2.y,0.f);
            u2[2][j4*4+2]=fmaxf(acc2.z,0.f); u2[2][j4*4+3]=fmaxf(acc2.w,0.f);
            u2[3][j4*4+0]=fmaxf(acc3.x,0.f); u2[3][j4*4+1]=fmaxf(acc3.y,0.f);
            u2[3][j4*4+2]=fmaxf(acc3.z,0.f); u2[3][j4*4+3]=fmaxf(acc3.w,0.f);
        }

        float u3[4][8];
        #pragma unroll
        for (int j2 = 0; j2 < 2; j2++){
            float4 acc0 = B34[j2], acc1 = acc0, acc2 = acc0, acc3 = acc0;
            #pragma unroll
            for (int c = 0; c < 16; c++){
                float4 w = W34[c*2 + j2];
                FMA4(acc0, u2[0][c], w); FMA4(acc1, u2[1][c], w);
                FMA4(acc2, u2[2][c], w); FMA4(acc3, u2[3][c], w);
            }
            u3[0][j2*4+0]=fmaxf(acc0.x,0.f); u3[0][j2*4+1]=fmaxf(acc0.y,0.f);
            u3[0][j2*4+2]=fmaxf(acc0.z,0.f); u3[0][j2*4+3]=fmaxf(acc0.w,0.f);
            u3[1][j2*4+0]=fmaxf(acc1.x,0.f); u3[1][j2*4+1]=fmaxf(acc1.y,0.f);
            u3[1][j2*4+2]=fmaxf(acc1.z,0.f); u3[1][j2*4+3]=fmaxf(acc1.w,0.f);
            u3[2][j2*4+0]=fmaxf(acc2.x,0.f); u3[2][j2*4+1]=fmaxf(acc2.y,0.f);
            u3[2][j2*4+2]=fmaxf(acc2.z,0.f); u3[2][j2*4+3]=fmaxf(acc2.w,0.f);
            u3[3][j2*4+0]=fmaxf(acc3.x,0.f); u3[3][j2*4+1]=fmaxf(acc3.y,0.f);
            u3[3][j2*4+2]=fmaxf(acc3.z,0.f); u3[3][j2*4+3]=fmaxf(acc3.w,0.f);
        }

        float4 ev[4];
        {
            float4 b4v = *(const float4*)(L + 632);
            ev[0] = b4v; ev[1] = b4v; ev[2] = b4v; ev[3] = b4v;
            #pragma unroll
            for (int c = 0; c < 8; c++){
                float4 w = W44[c];
                FMA4(ev[0], u3[0][c], w); FMA4(ev[1], u3[1][c], w);
                FMA4(ev[2], u3[2][c], w); FMA4(ev[3], u3[3][c], w);
            }
        }

        #pragma unroll
        for (int k = 0; k < 4; k++){
            float4 e4 = ev[k];
            float mx = fmaxf(fmaxf(e4.x, e4.y), fmaxf(e4.z, e4.w));
            float ls = logf(expf(e4.x-mx)+expf(e4.y-mx)+expf(e4.z-mx)+expf(e4.w-mx)) + mx;
            float4 o;
            o.x = e4.x-ls; o.y = e4.y-ls; o.z = e4.z-ls; o.w = e4.w-ls;
            ((float4*)oute)[e0+k] = o;
            float et = e4.x*sg2v[0] + e4.y*sg2v[1] + e4.z*sg2v[2] + e4.w*sg2v[3];
            etsum += et;
            sg[stash[k]].y = lrelu(hsd[k] + et);
        }
    } else if (e0 < E){
        for (int e = e0; e < E; e++){
            int sp;
            if (rank) sp = (int)(rowptr[ei[E+e]] + rank[e]);
            else      sp = posStash[4*(size_t)e];
            int si = ei[e], di = ei[E+e];
            float4 xs = ((const float4*)xagg)[si];
            float4 xd = ((const float4*)xagg)[di];
            size_t eo = 3*(size_t)e;
            float e0v = ea[eo], e1v = ea[eo+1], e2v = ea[eo+2];
            float u1s[16];
            #pragma unroll
            for (int j4 = 0; j4 < 4; j4++){
                float4 acc = bb4[j4];
                FMA4(acc, xs.x, A4[0*4+j4]); FMA4(acc, xs.y, A4[1*4+j4]);
                FMA4(acc, xs.z, A4[2*4+j4]); FMA4(acc, xs.w, A4[3*4+j4]);
                FMA4(acc, e0v, C34[0*4+j4]); FMA4(acc, e1v, C34[1*4+j4]);
                FMA4(acc, e2v, C34[2*4+j4]);
                FMA4(acc, xd.x, B4[0*4+j4]); FMA4(acc, xd.y, B4[1*4+j4]);
                FMA4(acc, xd.z, B4[2*4+j4]); FMA4(acc, xd.w, B4[3*4+j4]);
                u1s[j4*4+0]=fmaxf(acc.x,0.f); u1s[j4*4+1]=fmaxf(acc.y,0.f);
                u1s[j4*4+2]=fmaxf(acc.z,0.f); u1s[j4*4+3]=fmaxf(acc.w,0.f);
            }
            float u2s[16];
            #pragma unroll
            for (int j4 = 0; j4 < 4; j4++){
                float4 acc = B24[j4];
                #pragma unroll
                for (int c = 0; c < 16; c++) FMA4(acc, u1s[c], W24[c*4+j4]);
                u2s[j4*4+0]=fmaxf(acc.x,0.f); u2s[j4*4+1]=fmaxf(acc.y,0.f);
                u2s[j4*4+2]=fmaxf(acc.z,0.f); u2s[j4*4+3]=fmaxf(acc.w,0.f);
            }
            float u3s[8];
            #pragma unroll
            for (int j2 = 0; j2 < 2; j2++){
                float4 acc = B34[j2];
                #pragma unroll
                for (int c = 0; c < 16; c++) FMA4(acc, u2s[c], W34[c*2+j2]);
                u3s[j2*4+0]=fmaxf(acc.x,0.f); u3s[j2*4+1]=fmaxf(acc.y,0.f);
                u3s[j2*4+2]=fmaxf(acc.z,0.f); u3s[j2*4+3]=fmaxf(acc.w,0.f);
            }
            float4 e4 = *(const float4*)(L + 632);
            #pragma unroll
            for (int c = 0; c < 8; c++) FMA4(e4, u3s[c], W44[c]);
            float mx = fmaxf(fmaxf(e4.x, e4.y), fmaxf(e4.z, e4.w));
            float ls = logf(expf(e4.x-mx)+expf(e4.y-mx)+expf(e4.z-mx)+expf(e4.w-mx)) + mx;
            float4 o;
            o.x = e4.x-ls; o.y = e4.y-ls; o.z = e4.z-ls; o.w = e4.w-ls;
            ((float4*)oute)[e] = o;
            float et = e4.x*sg2v[0] + e4.y*sg2v[1] + e4.z*sg2v[2] + e4.w*sg2v[3];
            etsum += et;
            float hs2 = xs.x*SD[0] + xs.y*SD[1] + xs.z*SD[2] + xs.w*SD[3] + SD[4];
            float hd2 = xd.x*SD[5] + xd.y*SD[6] + xd.z*SD[7] + xd.w*SD[8] + SD[9];
            sg[sp].y = lrelu(hs2 + hd2 + et);
        }
    }
    R[threadIdx.x] = etsum;
    __syncthreads();
    for (int off = 128; off > 0; off >>= 1){
        if (threadIdx.x < off) R[threadIdx.x] += R[threadIdx.x + off];
        __syncthreads();
    }
    if (threadIdx.x == 0) atomicAdd(&qw[3], R[0]);
}

// ---------- layer 2: single-pass online softmax, fused output ----------
__global__ void __launch_bounds__(256)
k_l2(const unsigned int* __restrict__ rowptr,
     const float2* __restrict__ sg, const float* __restrict__ xagg,
     const float2* __restrict__ h2t,
     const float* __restrict__ q, const float* __restrict__ b2,
     float* __restrict__ outn, float invE, int N)
{
    __shared__ float sq[64];
    if (threadIdx.x < 64) sq[threadIdx.x] = q[threadIdx.x];
    __syncthreads();
    int d = blockIdx.x*256 + threadIdx.x;
    if (d >= N) return;
    float c2 = sq[3] * invE;
    float4 xa = ((const float4*)xagg)[d];
    float h2d0 = xa.x*sq[28] + xa.y*sq[30] + xa.z*sq[32] + xa.w*sq[34] + sq[36];
    float h2d1 = xa.x*sq[29] + xa.y*sq[31] + xa.z*sq[33] + xa.w*sq[35] + sq[37];
    float hs2 = xa.x*sq[40] + xa.y*sq[41] + xa.z*sq[42] + xa.w*sq[43] + sq[44];
    float hd2 = xa.x*sq[45] + xa.y*sq[46] + xa.z*sq[47] + xa.w*sq[48] + sq[49];
    float aself = lrelu(hs2 + hd2 + c2);

    float mA = aself, zA = 1.f, a0A = h2d0, a1A = h2d1;
    float mB = -1e30f, zB = 0.f, a0B = 0.f, a1B = 0.f;

    unsigned int beg = rowptr[d], end = rowptr[d+1];
    unsigned int j = beg;
    for (; j + 1 < end; j += 2){
        float2 r0 = sg[j];
        float2 r1 = sg[j+1];
        int s0 = __float_as_int(r0.x);
        int s1 = __float_as_int(r1.x);
        float h00, h01, h10, h11;
        if (h2t){
            float2 hh0 = h2t[s0];
            float2 hh1 = h2t[s1];
            h00 = hh0.x; h01 = hh0.y; h10 = hh1.x; h11 = hh1.y;
        } else {
            float4 xs0 = ((const float4*)xagg)[s0];
            float4 xs1 = ((const float4*)xagg)[s1];
            h00 = xs0.x*sq[28] + xs0.y*sq[30] + xs0.z*sq[32] + xs0.w*sq[34] + sq[36];
            h01 = xs0.x*sq[29] + xs0.y*sq[31] + xs0.z*sq[33] + xs0.w*sq[35] + sq[37];
            h10 = xs1.x*sq[28] + xs1.y*sq[30] + xs1.z*sq[32] + xs1.w*sq[34] + sq[36];
            h11 = xs1.x*sq[29] + xs1.y*sq[31] + xs1.z*sq[33] + xs1.w*sq[35] + sq[37];
        }
        float mn0 = fmaxf(mA, r0.y);
        float sc0 = expf(mA - mn0);
        float p0  = expf(r0.y - mn0);
        zA  = zA*sc0 + p0;
        a0A = a0A*sc0 + p0*h00;
        a1A = a1A*sc0 + p0*h01;
        mA = mn0;
        float mn1 = fmaxf(mB, r1.y);
        float sc1 = expf(mB - mn1);
        float p1  = expf(r1.y - mn1);
        zB  = zB*sc1 + p1;
        a0B = a0B*sc1 + p1*h10;
        a1B = a1B*sc1 + p1*h11;
        mB = mn1;
    }
    if (j < end){
        float2 r0 = sg[j];
        int s0 = __float_as_int(r0.x);
        float h00, h01;
        if (h2t){
            float2 hh0 = h2t[s0];
            h00 = hh0.x; h01 = hh0.y;
        } else {
            float4 xs0 = ((const float4*)xagg)[s0];
            h00 = xs0.x*sq[28] + xs0.y*sq[30] + xs0.z*sq[32] + xs0.w*sq[34] + sq[36];
            h01 = xs0.x*sq[29] + xs0.y*sq[31] + xs0.z*sq[33] + xs0.w*sq[35] + sq[37];
        }
        float mn0 = fmaxf(mA, r0.y);
        float sc0 = expf(mA - mn0);
        float p0  = expf(r0.y - mn0);
        zA  = zA*sc0 + p0;
        a0A = a0A*sc0 + p0*h00;
        a1A = a1A*sc0 + p0*h01;
        mA = mn0;
    }
    float m = fmaxf(mA, mB);
    float sA = expf(mA - m), sB = expf(mB - m);
    float z = zA*sA + zB*sB;
    float inv = 1.0f / z;
    float v0 = (a0A*sA + a0B*sB)*inv + b2[0];
    float v1 = (a1A*sA + a1B*sB)*inv + b2[1];
    float mm = fmaxf(v0, v1);
    float ls = logf(expf(v0-mm) + expf(v1-mm)) + mm;
    float2 o;
    o.x = v0 - ls;
    o.y = v1 - ls;
    ((float2*)outn)[d] = o;
}

extern "C" void kernel_launch(void* const* d_in, const int* in_sizes, int n_in,
                              void* d_out, int out_size, void* d_ws, size_t ws_size,
                              hipStream_t stream)
{
    const float* x   = (const float*)d_in[0];
    const int*   ei  = (const int*)  d_in[1];
    const float* ea  = (const float*)d_in[2];
    const float* W1  = (const float*)d_in[3];
    const float* as1 = (const float*)d_in[4];
    const float* ad1 = (const float*)d_in[5];
    const float* We1 = (const float*)d_in[6];
    const float* ae1 = (const float*)d_in[7];
    const float* b1  = (const float*)d_in[8];
    const float* Wm1 = (const float*)d_in[9];
    const float* bm1 = (const float*)d_in[10];
    const float* Wm2 = (const float*)d_in[11];
    const float* bm2 = (const float*)d_in[12];
    const float* Wm3 = (const float*)d_in[13];
    const float* bm3 = (const float*)d_in[14];
    const float* Wm4 = (const float*)d_in[15];
    const float* bm4 = (const float*)d_in[16];
    const float* W2  = (const float*)d_in[17];
    const float* as2 = (const float*)d_in[18];
    const float* ad2 = (const float*)d_in[19];
    const float* We2 = (const float*)d_in[20];
    const float* ae2 = (const float*)d_in[21];
    const float* b2  = (const float*)d_in[22];

    const int N = in_sizes[0] / 4;
    const int E = in_sizes[1] / 2;

    int nb_n = (N + 255) / 256;
    int nb_e = (E + 255) / 256;
    int nb_e4 = (E + 1023) / 1024;
    if (nb_n > 1024) return;

    // common: q(256) | cnt(N u32) | rowptr(N+64 u32) | aux(1024 u32) | xagg(4N) | sg(2E)
    size_t commonFloats = 256 + (size_t)N + ((size_t)N + 64) + 1024 + 4*(size_t)N + 2*(size_t)E;
    // upgraded: + h2t(2N) + rank(E u16 -> E/2+16 floats)
    size_t upFloats = commonFloats + 2*(size_t)N + ((size_t)E/2 + 16);
    if (ws_size < commonFloats*sizeof(float)) return;
    bool up = (ws_size >= upFloats*sizeof(float));

    float* ws = (float*)d_ws;
    float* q  = ws;
    unsigned int* cnt    = (unsigned int*)(ws + 256);
    unsigned int* rowptr = cnt + N;
    unsigned int* aux    = rowptr + N + 64;
    float* xagg = (float*)(aux + 1024);
    float2* sg  = (float2*)(xagg + 4*(size_t)N);
    float2* h2t = nullptr;
    unsigned short* rank = nullptr;
    if (up){
        h2t  = (float2*)(sg + (size_t)E);
        rank = (unsigned short*)(h2t + (size_t)N);
    }

    float* outn = (float*)d_out;
    float* oute = outn + 2*(size_t)N;
    int* posStash = (int*)oute;   // fallback stash (each edge's own oute slot)

    // zero q + cnt
    hipMemsetAsync(d_ws, 0, (256 + (size_t)N)*sizeof(float), stream);

    float invE = 1.0f / (float)E;

    k_hist<<<1024,256,0,stream>>>(ei, ea, q, cnt, rank, E);
    k_prep<<<1,64,0,stream>>>(W1, as1, ad1, We1, ae1, b1, Wm1, bm1,
                              W2, as2, ad2, We2, ae2, q, invE);
    k_scan1<<<nb_n,256,0,stream>>>(cnt, rowptr, aux, N);
    k_scan2<<<1,1024,0,stream>>>(aux, nb_n);
    k_scan3<<<nb_n,256,0,stream>>>(rowptr, cnt, aux, N, E);   // cnt becomes insert ptrs (fallback)
    k_scatter<<<nb_e,256,0,stream>>>(ei, ea, q, rowptr, rank, cnt, sg, posStash, E);
    k_l1<<<nb_n,256,0,stream>>>(rowptr, sg, x, q, xagg, h2t, N);
    k_mlp<<<nb_e4,256,0,stream>>>(ei, ea, xagg, Wm1, Wm2, bm2, Wm3, bm3,
                                  Wm4, bm4, q, q, sg, rowptr, rank, posStash, oute, E);
    k_l2<<<nb_n,256,0,stream>>>(rowptr, sg, xagg, h2t, q, b2, outn, invE, N);
}